// Round 17
// baseline (263.238 us; speedup 1.0000x reference)
//
#include <hip/hip_runtime.h>

#define K_CODES 1024
#define DIM 64
#define B_ 16
#define T_ 8192
#define N_ (B_*T_)          // 131072 vectors
#define EPSF 1e-5f
#define SMARGIN 5e-4f       // exact-float margin; > 2x the 7-bit key quantum 2.44e-4
#define MSK7 0xFFFFFF80u

typedef __attribute__((ext_vector_type(8))) short short8;   // 8 bf16 = 4 VGPR
typedef __attribute__((ext_vector_type(4))) float f32x4;

typedef __attribute__((address_space(1))) unsigned char g1_t;   // global
typedef __attribute__((address_space(3))) unsigned char l3_t;   // LDS

__device__ __forceinline__ unsigned bf16_rne(float f) {
    unsigned u = __float_as_uint(f);
    return (u + 0x7fffu + ((u >> 16) & 1u)) >> 16;
}
__device__ __forceinline__ unsigned umx(unsigned a, unsigned b) { return a > b ? a : b; }
__device__ __forceinline__ unsigned umn(unsigned a, unsigned b) { return a < b ? a : b; }

// ---- prep: e -> bf16 hi/lo tables, fp64 table, norms; zero accumulators ----
__global__ __launch_bounds__(64) void vq_prep(const float* __restrict__ emb,
                                              double* __restrict__ e64,
                                              double* __restrict__ snh64,
                                              float* __restrict__ snb32,
                                              unsigned short* __restrict__ ehib,
                                              unsigned short* __restrict__ elob,
                                              int* __restrict__ counts,
                                              int* __restrict__ cnt2,
                                              int* __restrict__ flagcnt) {
    const int k = blockIdx.x;
    const int d = threadIdx.x;
    if (d == 0) counts[k] = 0;
    if (d == 1) cnt2[k] = 0;
    if (k == 0 && d == 2) *flagcnt = 0;

    const float ef = emb[k * DIM + d];
    const unsigned rh = bf16_rne(ef);
    const float hif = __uint_as_float(rh << 16);
    const float lof = ef - hif;                   // exact (Sterbenz)
    const unsigned rl = bf16_rne(lof);
    ehib[k * DIM + d] = (unsigned short)rh;
    elob[k * DIM + d] = (unsigned short)rl;

    const double ed = (double)ef;
    e64[k * DIM + d] = ed;
    double s = ed * ed;
    #pragma unroll
    for (int off = 32; off; off >>= 1) s += __shfl_down(s, off, 64);
    if (d == 0) {
        snh64[k] = 0.5 * s;
        snb32[k] = (float)(16.0 - 0.5 * s);   // +16 bias: scores in (8,24), positive
    }
}

// ---- screen: nt=8 (128 vec/wave), barrier-free counted-vmcnt staging ----
// block = 128 thr = 2 waves (khalf 0/1), both over the same 128 vectors; grid 1024.
__global__ __launch_bounds__(128) void vq_screen(const float* __restrict__ x,
                                                 const unsigned short* __restrict__ ehib,
                                                 const unsigned short* __restrict__ elob,
                                                 const float* __restrict__ snb32,
                                                 const float* __restrict__ emb,
                                                 float* __restrict__ out,
                                                 float* __restrict__ xT,
                                                 int* __restrict__ idx32,
                                                 int* __restrict__ counts,
                                                 int* __restrict__ flagcnt,
                                                 int* __restrict__ flagids,
                                                 int use_xt) {
    __shared__ unsigned short stg[2][2][2048]; // [khalf][buf][hi 2KB | lo 2KB] private/wave
    __shared__ float snl[K_CODES];             // biased norms, staged once
    __shared__ float red[128][4];              // khalf=1: b1, b2, idx-bits
    __shared__ int sidx[128];                  // merged: code index, or -1 = flagged

    const int tid   = threadIdx.x;
    const int khalf = tid >> 6;                // wave 0: codes 0-511; wave 1: 512-1023
    const int lane  = tid & 63;
    const int ln15  = lane & 15;
    const int lhi   = lane >> 4;               // 0..3

    const int blk  = blockIdx.x;               // 1024 blocks x 128 vectors
    const int b    = blk >> 6;                 // 64 blocks per batch row
    const int tblk = (blk & 63) << 7;
    const float* xb = x + ((size_t)b << 19);

    // ---- stage this wave's 512 biased norms to LDS (2 x 1KB, wave-private) ----
    {
        const unsigned char* gs = (const unsigned char*)(snb32 + (khalf << 9));
        unsigned char* ls = (unsigned char*)&snl[khalf << 9];
        __builtin_amdgcn_global_load_lds((const g1_t*)(gs + lane * 16),        (l3_t*)ls,          16, 0, 0);
        __builtin_amdgcn_global_load_lds((const g1_t*)(gs + 1024 + lane * 16), (l3_t*)(ls + 1024), 16, 0, 0);
    }

    // ---- x B-fragments (hi/lo), register-resident; 8 n-tiles = 128 vectors ----
    short8 xbh[8][2], xbl[8][2];
    #pragma unroll
    for (int nt = 0; nt < 8; nt++) {
        const int t = tblk + nt * 16 + ln15;
        #pragma unroll
        for (int s = 0; s < 2; s++) {
            #pragma unroll
            for (int j = 0; j < 8; j++) {
                const int d = s * 32 + lhi * 8 + j;
                const float xf = xb[((size_t)d << 13) + t];
                const unsigned rh = bf16_rne(xf);
                const float hif = __uint_as_float(rh << 16);
                const unsigned rl = bf16_rne(xf - hif);
                xbh[nt][s][j] = (short)rh;
                xbl[nt][s][j] = (short)rl;
            }
        }
    }

    // staging: pre-swizzled source byte offset (G4 swizzle, rule 21)
    const int srow = lane >> 3;
    const int soff = (srow << 7) + (((lane & 7) ^ srow) << 4);
    const int rx = ln15 & 7;
    const int c0 = (lhi ^ rx) << 3;
    const int c1 = ((4 + lhi) ^ rx) << 3;
    const int rbase = ln15 * 64;

    const int kbase = khalf << 9;

// wave-private: all 4 chunks (hi 2KB + lo 2KB) staged by this wave into its own buf
#define STAGE(BUF, KT) { \
    const size_t tb_ = (size_t)(kbase + ((KT) << 4)) * DIM; \
    const unsigned char* gh_ = (const unsigned char*)(ehib + tb_) + soff; \
    const unsigned char* gl_ = (const unsigned char*)(elob + tb_) + soff; \
    unsigned char* lb_ = (unsigned char*)&stg[khalf][BUF][0]; \
    __builtin_amdgcn_global_load_lds((const g1_t*)gh_,          (l3_t*)lb_,          16, 0, 0); \
    __builtin_amdgcn_global_load_lds((const g1_t*)(gh_ + 1024), (l3_t*)(lb_ + 1024), 16, 0, 0); \
    __builtin_amdgcn_global_load_lds((const g1_t*)gl_,          (l3_t*)(lb_ + 2048), 16, 0, 0); \
    __builtin_amdgcn_global_load_lds((const g1_t*)(gl_ + 1024), (l3_t*)(lb_ + 3072), 16, 0, 0); \
}

    // packed keys: high 25 bits = positive-score float bits, low 7 = 127-local
    unsigned b1k[8] = {0,0,0,0,0,0,0,0}, b2k[8] = {0,0,0,0,0,0,0,0};

#define BODY(BUF, KT, DOPRE, NKT) { \
    if (DOPRE) { \
        STAGE((BUF) ^ 1, NKT) \
        asm volatile("s_waitcnt vmcnt(4)" ::: "memory");   /* prev tile landed */ \
    } else { \
        asm volatile("s_waitcnt vmcnt(0)" ::: "memory");   /* last tile: drain */ \
    } \
    const unsigned short* lb = &stg[khalf][BUF][0]; \
    const short8 ah0 = *(const short8*)(lb + rbase + c0); \
    const short8 ah1 = *(const short8*)(lb + rbase + c1); \
    const short8 al0 = *(const short8*)(lb + 1024 + rbase + c0); \
    const short8 al1 = *(const short8*)(lb + 1024 + rbase + c1); \
    const int k0_ = kbase + ((KT) << 4); \
    const f32x4 bias = *(const f32x4*)(&snl[k0_ + lhi * 4]); \
    const unsigned revb = 127u - (unsigned)((KT) << 2); \
    _Pragma("unroll") \
    for (int nt = 0; nt < 8; nt++) { \
        f32x4 acc = bias; \
        acc = __builtin_amdgcn_mfma_f32_16x16x32_bf16(ah0, xbh[nt][0], acc, 0, 0, 0); \
        acc = __builtin_amdgcn_mfma_f32_16x16x32_bf16(ah1, xbh[nt][1], acc, 0, 0, 0); \
        acc = __builtin_amdgcn_mfma_f32_16x16x32_bf16(ah0, xbl[nt][0], acc, 0, 0, 0); \
        acc = __builtin_amdgcn_mfma_f32_16x16x32_bf16(ah1, xbl[nt][1], acc, 0, 0, 0); \
        acc = __builtin_amdgcn_mfma_f32_16x16x32_bf16(al0, xbh[nt][0], acc, 0, 0, 0); \
        acc = __builtin_amdgcn_mfma_f32_16x16x32_bf16(al1, xbh[nt][1], acc, 0, 0, 0); \
        _Pragma("unroll") \
        for (int r = 0; r < 4; r++) { \
            const unsigned key = (__float_as_uint(acc[r]) & MSK7) | (revb - r); \
            b2k[nt] = umx(b2k[nt], umn(b1k[nt], key)); \
            b1k[nt] = umx(b1k[nt], key); \
        } \
    } \
}

    STAGE(0, 0)
    #pragma unroll 1
    for (int kt2 = 0; kt2 < 32; kt2 += 2) {
        BODY(0, kt2, 1, kt2 + 1)
        BODY(1, kt2 + 1, (kt2 < 30), kt2 + 2)
    }
#undef STAGE
#undef BODY

    // ---- unpack, then merge top-2 across the 4 lane-groups ----
    #pragma unroll
    for (int nt = 0; nt < 8; nt++) {
        float B1 = __uint_as_float(b1k[nt] & MSK7);
        float B2 = __uint_as_float(b2k[nt] & MSK7);
        const int local = 127 - (int)(b1k[nt] & 127u);          // kt*4 + r
        int I = kbase + ((local >> 2) << 4) + lhi * 4 + (local & 3);
        #pragma unroll
        for (int off = 16; off <= 32; off <<= 1) {
            const float o1 = __shfl_xor(B1, off, 64);
            const float o2 = __shfl_xor(B2, off, 64);
            const int   oi = __shfl_xor(I,  off, 64);
            const float nb2 = fmaxf(fminf(B1, o1), fmaxf(B2, o2));
            if (o1 > B1 || (o1 == B1 && oi < I)) { B1 = o1; I = oi; }
            B2 = nb2;
        }
        if (lane < 16) {
            const int vloc = nt * 16 + lane;
            if (khalf == 1) {
                red[vloc][0] = B1; red[vloc][1] = B2; red[vloc][2] = __int_as_float(I);
            } else {
                sidx[vloc] = I;                              // park khalf-0 index
            }
        }
        b1k[nt] = __float_as_uint(B1); b2k[nt] = __float_as_uint(B2);
    }
    __syncthreads();

    if (khalf == 0) {
        #pragma unroll
        for (int nt = 0; nt < 8; nt++) {
            if (lane < 16) {
                const int vloc = nt * 16 + lane;
                const float ob1 = red[vloc][0];
                const float ob2 = red[vloc][1];
                const int   oi  = __float_as_int(red[vloc][2]);
                float B1 = __uint_as_float(b1k[nt]);
                float B2 = __uint_as_float(b2k[nt]);
                int I = sidx[vloc];
                if (ob1 > B1) { B2 = fmaxf(B1, ob2); B1 = ob1; I = oi; }  // kh0 idx < kh1 idx
                else          { B2 = fmaxf(B2, ob1); }
                sidx[vloc] = (B1 - B2 <= SMARGIN) ? -1 : I;
            }
        }
    }
    __syncthreads();

    // ---- epilogue: thread = vector (128 thr, 128 vec); writes out + xT ----
    const int vloc = tid;
    const int t    = tblk + vloc;
    const int I    = sidx[vloc];
    const int v    = (b << 13) + t;
    const float* xp = xb + t;

    if (I < 0) {
        const int p = atomicAdd(flagcnt, 1); flagids[p] = v;
        if (use_xt) {
            float4* xtp = (float4*)(xT + (size_t)v * 64);
            #pragma unroll
            for (int q = 0; q < 16; q++) {
                float4 w;
                w.x = xp[(size_t)(q * 4 + 0) << 13];
                w.y = xp[(size_t)(q * 4 + 1) << 13];
                w.z = xp[(size_t)(q * 4 + 2) << 13];
                w.w = xp[(size_t)(q * 4 + 3) << 13];
                xtp[q] = w;
            }
        }
    } else {
        idx32[v] = I;
        atomicAdd(&counts[I], 1);
        const float4* eq4 = (const float4*)(emb + I * DIM);
        float4* xtp = (float4*)(xT + (size_t)v * 64);
        #pragma unroll
        for (int q = 0; q < 16; q++) {
            const float4 e4 = eq4[q];
            float4 w;
            w.x = xp[(size_t)(q * 4 + 0) << 13];
            w.y = xp[(size_t)(q * 4 + 1) << 13];
            w.z = xp[(size_t)(q * 4 + 2) << 13];
            w.w = xp[(size_t)(q * 4 + 3) << 13];
            if (use_xt) xtp[q] = w;
            out[((size_t)b << 19) + ((size_t)(q * 4 + 0) << 13) + t] = w.x + (e4.x - w.x);
            out[((size_t)b << 19) + ((size_t)(q * 4 + 1) << 13) + t] = w.y + (e4.y - w.y);
            out[((size_t)b << 19) + ((size_t)(q * 4 + 2) << 13) + t] = w.z + (e4.z - w.z);
            out[((size_t)b << 19) + ((size_t)(q * 4 + 3) << 13) + t] = w.w + (e4.w - w.w);
        }
    }
}

// ---- rescan: wave = 4 vectors, e64 direct from L2, zero LDS / barriers ----
__global__ __launch_bounds__(256) void vq_rescan(const float* __restrict__ x,
                                                 const float* __restrict__ emb,
                                                 const double* __restrict__ e64,
                                                 const double* __restrict__ snh64,
                                                 float* __restrict__ out,
                                                 int* __restrict__ idx32,
                                                 int* __restrict__ counts,
                                                 const int* __restrict__ flagcnt,
                                                 const int* __restrict__ flagids) {
    const int tid   = threadIdx.x;
    const int wid   = tid >> 6;          // 4 waves/block
    const int lane  = tid & 63;
    const int cslot = lane >> 2;         // 0..15 code slot
    const int dg    = lane & 3;          // 16-dim group
    const int count = *flagcnt;

    for (int base = blockIdx.x * 16 + wid * 4; base < count; base += gridDim.x * 16) {
        bool act[4]; int vv[4];
        const float* xbp[4];
        double xd[4][16];
        #pragma unroll
        for (int vx = 0; vx < 4; vx++) {
            const int i = base + vx;
            act[vx] = i < count;
            const int v = flagids[act[vx] ? i : 0];
            vv[vx] = v;
            const int b = v >> 13, t = v & (T_ - 1);
            xbp[vx] = x + ((size_t)b << 19) + t;
            #pragma unroll
            for (int j = 0; j < 16; j++)
                xd[vx][j] = act[vx] ? (double)xbp[vx][(size_t)(dg * 16 + j) << 13] : 0.0;
        }

        double best[4] = {-1e300, -1e300, -1e300, -1e300};
        int    bi_[4]  = {0, 0, 0, 0};

        #pragma unroll 4
        for (int cc = 0; cc < 64; cc++) {
            const int k = cc * 16 + cslot;                // in-lane k ascends with cc
            const double* ek = e64 + (size_t)k * DIM + dg * 16;
            const double snh = snh64[k];
            #pragma unroll
            for (int vx = 0; vx < 4; vx++) {
                double a0 = 0.0, a1 = 0.0, a2 = 0.0, a3 = 0.0;
                #pragma unroll
                for (int j = 0; j < 16; j += 4) {
                    a0 = __fma_rn(xd[vx][j + 0], ek[j + 0], a0);
                    a1 = __fma_rn(xd[vx][j + 1], ek[j + 1], a1);
                    a2 = __fma_rn(xd[vx][j + 2], ek[j + 2], a2);
                    a3 = __fma_rn(xd[vx][j + 3], ek[j + 3], a3);
                }
                double a = (a0 + a1) + (a2 + a3);
                a += __shfl_xor(a, 1, 64);
                a += __shfl_xor(a, 2, 64);                // full dot over 4 dim-groups
                const double m = a - snh;
                if (m > best[vx]) { best[vx] = m; bi_[vx] = k; }
            }
        }

        #pragma unroll
        for (int vx = 0; vx < 4; vx++) {
            double bb = best[vx]; int ii = bi_[vx];
            #pragma unroll
            for (int off = 4; off <= 32; off <<= 1) {     // merge across cslots
                const double ob = __shfl_xor(bb, off, 64);
                const int    oi = __shfl_xor(ii, off, 64);
                if (ob > bb || (ob == bb && oi < ii)) { bb = ob; ii = oi; }
            }
            if (act[vx]) {                                // epilogue: lane = dim
                const int v = vv[vx];
                const int b = v >> 13, t = v & (T_ - 1);
                const float xf = xbp[vx][(size_t)lane << 13];
                out[((size_t)b << 19) + ((size_t)lane << 13) + t] =
                    xf + (emb[ii * DIM + lane] - xf);
                if (lane == 0) { idx32[v] = ii; atomicAdd(&counts[ii], 1); }
            }
        }
    }
}

// ---- scatter (scan fused): block-local scan of counts, then counting-sort ----
__global__ __launch_bounds__(256) void vq_scatter(const int* __restrict__ idx32,
                                                  const int* __restrict__ counts,
                                                  int* __restrict__ cnt2,
                                                  int* __restrict__ offsets,
                                                  int* __restrict__ order) {
    __shared__ int soff[K_CODES];
    __shared__ int wsum[4];
    const int tid  = threadIdx.x;
    const int lane = tid & 63;
    const int w    = tid >> 6;

    int c[4]; int tsum = 0;
    #pragma unroll
    for (int j = 0; j < 4; j++) { c[j] = counts[tid * 4 + j]; tsum += c[j]; }
    int s = tsum;
    #pragma unroll
    for (int off = 1; off < 64; off <<= 1) {
        const int o = __shfl_up(s, off, 64);
        if (lane >= off) s += o;
    }
    if (lane == 63) wsum[w] = s;
    __syncthreads();
    int wbase = 0;
    #pragma unroll
    for (int j = 0; j < 4; j++) wbase += (j < w) ? wsum[j] : 0;
    int excl = wbase + s - tsum;
    #pragma unroll
    for (int j = 0; j < 4; j++) { soff[tid * 4 + j] = excl; excl += c[j]; }
    __syncthreads();
    if (blockIdx.x == 0) {               // publish for vq_reduce
        #pragma unroll
        for (int j = 0; j < 4; j++) offsets[tid * 4 + j] = soff[tid * 4 + j];
    }

    const int v = blockIdx.x * 256 + tid;
    const int k = idx32[v];
    const int p = soff[k] + atomicAdd(&cnt2[k], 1);
    order[p] = v;
}

// ---- reduce: block per code, 256 thr (4-way i-split); sum / cluster_size ----
__global__ __launch_bounds__(256) void vq_reduce(const float* __restrict__ x,
                                                 const float* __restrict__ xT,
                                                 const int* __restrict__ order,
                                                 const int* __restrict__ offsets,
                                                 const int* __restrict__ counts,
                                                 float* __restrict__ newemb,
                                                 int use_xt) {
    __shared__ int lv[1024];
    __shared__ float ps[4][64];
    const int k = blockIdx.x;
    const int tid = threadIdx.x;
    const int i4 = tid >> 6;
    const int d = tid & 63;
    const int off = offsets[k];
    const int cnt = counts[k];
    float sum = 0.f;
    for (int base = 0; base < cnt; base += 1024) {
        const int m = min(1024, cnt - base);
        __syncthreads();
        for (int i = tid; i < m; i += 256) lv[i] = order[off + base + i];
        __syncthreads();
        if (use_xt) {
            for (int i = i4; i < m; i += 4) sum += xT[(size_t)lv[i] * 64 + d];
        } else {
            for (int i = i4; i < m; i += 4) {
                const int v = lv[i];
                sum += x[((size_t)(v >> 13) << 19) + ((size_t)d << 13) + (v & (T_ - 1))];
            }
        }
    }
    __syncthreads();
    ps[i4][d] = sum;
    __syncthreads();
    if (i4 == 0) {
        const float tot = ps[0][d] + ps[1][d] + ps[2][d] + ps[3][d];
        const float c = (float)cnt;
        const float cluster = (c + EPSF) / (131072.0f + 1024.0f * EPSF) * 131072.0f;
        newemb[k * DIM + d] = tot / cluster;
    }
}

extern "C" void kernel_launch(void* const* d_in, const int* in_sizes, int n_in,
                              void* d_out, int out_size, void* d_ws, size_t ws_size,
                              hipStream_t stream) {
    const float* x   = (const float*)d_in[0];
    const float* emb = (const float*)d_in[1];

    char* ws = (char*)d_ws;
    double*         e64     = (double*)(ws);                  //  524288 B
    double*         snh64   = (double*)(ws + 524288);         //    8192 B
    float*          snb32   = (float*)(ws + 532480);          //    4096 B
    unsigned short* ehib    = (unsigned short*)(ws + 536576); //  131072 B
    unsigned short* elob    = (unsigned short*)(ws + 667648); //  131072 B
    int*            idx32   = (int*)(ws + 798720);            //  524288 B
    int*            order   = (int*)(ws + 1323008);           //  524288 B
    int*            counts  = (int*)(ws + 1847296);           //    4096 B
    int*            flagcnt = (int*)(ws + 1851392);           //      64 B
    int*            offsets = (int*)(ws + 1851456);           //    4096 B
    int*            cnt2    = (int*)(ws + 1855552);           //    4096 B
    int*            flagids = (int*)(ws + 1859648);           //  524288 B
    float*          xT      = (float*)(ws + 2383936);         // 33554432 B (optional)
    const int use_xt = (ws_size >= (size_t)2383936 + 33554432) ? 1 : 0;

    float* out    = (float*)d_out;
    float* newemb = out + (size_t)B_ * DIM * T_;

    vq_prep<<<K_CODES, 64, 0, stream>>>(emb, e64, snh64, snb32, ehib, elob,
                                        counts, cnt2, flagcnt);
    vq_screen<<<N_ / 128, 128, 0, stream>>>(x, ehib, elob, snb32, emb, out, xT, idx32,
                                            counts, flagcnt, flagids, use_xt);
    vq_rescan<<<512, 256, 0, stream>>>(x, emb, e64, snh64, out, idx32, counts,
                                       flagcnt, flagids);
    vq_scatter<<<N_ / 256, 256, 0, stream>>>(idx32, counts, cnt2, offsets, order);
    vq_reduce<<<K_CODES, 256, 0, stream>>>(x, xT, order, offsets, counts, newemb, use_xt);
}

// Round 18
// 211.370 us; speedup vs baseline: 1.2454x; 1.2454x over previous
//
#include <hip/hip_runtime.h>

#define K_CODES 1024
#define DIM 64
#define B_ 16
#define T_ 8192
#define N_ (B_*T_)          // 131072 vectors
#define EPSF 1e-5f
#define SMARGIN 5e-4f       // exact-float margin; > 2x the 7-bit key quantum 2.44e-4
#define MSK7 0xFFFFFF80u

typedef __attribute__((ext_vector_type(8))) short short8;   // 8 bf16 = 4 VGPR
typedef __attribute__((ext_vector_type(4))) float f32x4;

typedef __attribute__((address_space(1))) unsigned char g1_t;   // global
typedef __attribute__((address_space(3))) unsigned char l3_t;   // LDS

__device__ __forceinline__ unsigned bf16_rne(float f) {
    unsigned u = __float_as_uint(f);
    return (u + 0x7fffu + ((u >> 16) & 1u)) >> 16;
}
__device__ __forceinline__ unsigned umx(unsigned a, unsigned b) { return a > b ? a : b; }
__device__ __forceinline__ unsigned umn(unsigned a, unsigned b) { return a < b ? a : b; }

// ---- prep: e -> bf16 hi/lo tables, fp64 table, norms; zero accumulators ----
__global__ __launch_bounds__(64) void vq_prep(const float* __restrict__ emb,
                                              double* __restrict__ e64,
                                              double* __restrict__ snh64,
                                              float* __restrict__ snb32,
                                              unsigned short* __restrict__ ehib,
                                              unsigned short* __restrict__ elob,
                                              int* __restrict__ counts,
                                              int* __restrict__ cnt2,
                                              int* __restrict__ flagcnt) {
    const int k = blockIdx.x;
    const int d = threadIdx.x;
    if (d == 0) counts[k] = 0;
    if (d == 1) cnt2[k] = 0;
    if (k == 0 && d == 2) *flagcnt = 0;

    const float ef = emb[k * DIM + d];
    const unsigned rh = bf16_rne(ef);
    const float hif = __uint_as_float(rh << 16);
    const float lof = ef - hif;                   // exact (Sterbenz)
    const unsigned rl = bf16_rne(lof);
    ehib[k * DIM + d] = (unsigned short)rh;
    elob[k * DIM + d] = (unsigned short)rl;

    const double ed = (double)ef;
    e64[k * DIM + d] = ed;
    double s = ed * ed;
    #pragma unroll
    for (int off = 32; off; off >>= 1) s += __shfl_down(s, off, 64);
    if (d == 0) {
        snh64[k] = 0.5 * s;
        snb32[k] = (float)(16.0 - 0.5 * s);   // +16 bias: scores in (8,24), positive
    }
}

// ---- screen: split-bf16 MFMA, packed-key top-2, LDS-staged e (dbuf+swz) ----
// block = 4 waves = 2 vgrp(64 vec) x 2 khalf(512 codes); 128 vec/block; grid 1024.
__global__ __launch_bounds__(256) void vq_screen(const float* __restrict__ x,
                                                 const unsigned short* __restrict__ ehib,
                                                 const unsigned short* __restrict__ elob,
                                                 const float* __restrict__ snb32,
                                                 const float* __restrict__ emb,
                                                 float* __restrict__ out,
                                                 float* __restrict__ xT,
                                                 int* __restrict__ idx32,
                                                 int* __restrict__ counts,
                                                 int* __restrict__ flagcnt,
                                                 int* __restrict__ flagids,
                                                 int use_xt) {
    __shared__ unsigned short stg[2][2][2048]; // [khalf][buf][hi 1024hw | lo 1024hw]
    __shared__ float red[128][4];              // khalf=1: b1, b2, idx-bits
    __shared__ int sidx[128];                  // merged: code index, or -1 = flagged
    __shared__ int hcnt[K_CODES];              // per-block histogram

    const int tid   = threadIdx.x;
    const int wid   = tid >> 6;
    const int lane  = tid & 63;
    const int vgrp  = wid & 1;
    const int khalf = wid >> 1;
    const int ln15  = lane & 15;
    const int lhi   = lane >> 4;               // 0..3

    #pragma unroll
    for (int q = 0; q < 4; q++) hcnt[tid + q * 256] = 0;

    const int blk  = blockIdx.x;               // 1024 blocks x 128 vectors
    const int b    = blk >> 6;
    const int tblk = (blk & 63) << 7;
    const int t0   = tblk + vgrp * 64;
    const float* xb = x + ((size_t)b << 19);

    // ---- x B-fragments (hi/lo), register-resident ----
    short8 xbh[4][2], xbl[4][2];
    #pragma unroll
    for (int nt = 0; nt < 4; nt++) {
        const int t = t0 + nt * 16 + ln15;
        #pragma unroll
        for (int s = 0; s < 2; s++) {
            #pragma unroll
            for (int j = 0; j < 8; j++) {
                const int d = s * 32 + lhi * 8 + j;
                const float xf = xb[((size_t)d << 13) + t];
                const unsigned rh = bf16_rne(xf);
                const float hif = __uint_as_float(rh << 16);
                const unsigned rl = bf16_rne(xf - hif);
                xbh[nt][s][j] = (short)rh;
                xbl[nt][s][j] = (short)rl;
            }
        }
    }

    // staging: pre-swizzled source byte offset (G4 swizzle, rule 21)
    const int srow = lane >> 3;
    const int soff = (srow << 7) + (((lane & 7) ^ srow) << 4);
    const int rx = ln15 & 7;
    const int c0 = (lhi ^ rx) << 3;
    const int c1 = ((4 + lhi) ^ rx) << 3;
    const int rbase = ln15 * 64;

    const int kbase = khalf << 9;

#define STAGE(BUF, KT) { \
    const size_t tb_ = (size_t)(kbase + ((KT) << 4)) * DIM; \
    if (vgrp == 0) { \
        const unsigned char* g_ = (const unsigned char*)(ehib + tb_) + soff; \
        unsigned short* l_ = &stg[khalf][BUF][0]; \
        __builtin_amdgcn_global_load_lds((const g1_t*)g_,          (l3_t*)l_,          16, 0, 0); \
        __builtin_amdgcn_global_load_lds((const g1_t*)(g_ + 1024), (l3_t*)(l_ + 512),  16, 0, 0); \
    } else { \
        const unsigned char* g_ = (const unsigned char*)(elob + tb_) + soff; \
        unsigned short* l_ = &stg[khalf][BUF][1024]; \
        __builtin_amdgcn_global_load_lds((const g1_t*)g_,          (l3_t*)l_,          16, 0, 0); \
        __builtin_amdgcn_global_load_lds((const g1_t*)(g_ + 1024), (l3_t*)(l_ + 512),  16, 0, 0); \
    } \
}

    // packed keys: high 25 bits = positive-score float bits, low 7 = 127-local
    unsigned b1k[4] = {0, 0, 0, 0}, b2k[4] = {0, 0, 0, 0};

#define BODY(BUF, KT, DOPRE, NKT) { \
    if (DOPRE) STAGE((BUF) ^ 1, NKT) \
    const unsigned short* lb = &stg[khalf][BUF][0]; \
    const short8 ah0 = *(const short8*)(lb + rbase + c0); \
    const short8 ah1 = *(const short8*)(lb + rbase + c1); \
    const short8 al0 = *(const short8*)(lb + 1024 + rbase + c0); \
    const short8 al1 = *(const short8*)(lb + 1024 + rbase + c1); \
    const int k0_ = kbase + ((KT) << 4); \
    const f32x4 bias = *(const f32x4*)(snb32 + k0_ + lhi * 4); \
    const unsigned revb = 127u - (unsigned)((KT) << 2); \
    _Pragma("unroll") \
    for (int nt = 0; nt < 4; nt++) { \
        f32x4 acc = bias; \
        acc = __builtin_amdgcn_mfma_f32_16x16x32_bf16(ah0, xbh[nt][0], acc, 0, 0, 0); \
        acc = __builtin_amdgcn_mfma_f32_16x16x32_bf16(ah1, xbh[nt][1], acc, 0, 0, 0); \
        acc = __builtin_amdgcn_mfma_f32_16x16x32_bf16(ah0, xbl[nt][0], acc, 0, 0, 0); \
        acc = __builtin_amdgcn_mfma_f32_16x16x32_bf16(ah1, xbl[nt][1], acc, 0, 0, 0); \
        acc = __builtin_amdgcn_mfma_f32_16x16x32_bf16(al0, xbh[nt][0], acc, 0, 0, 0); \
        acc = __builtin_amdgcn_mfma_f32_16x16x32_bf16(al1, xbh[nt][1], acc, 0, 0, 0); \
        _Pragma("unroll") \
        for (int r = 0; r < 4; r++) { \
            const unsigned key = (__float_as_uint(acc[r]) & MSK7) | (revb - r); \
            b2k[nt] = umx(b2k[nt], umn(b1k[nt], key)); \
            b1k[nt] = umx(b1k[nt], key); \
        } \
    } \
    __syncthreads(); \
}

    STAGE(0, 0)
    __syncthreads();
    #pragma unroll 1
    for (int kt2 = 0; kt2 < 32; kt2 += 2) {
        BODY(0, kt2, 1, kt2 + 1)
        BODY(1, kt2 + 1, (kt2 < 30), kt2 + 2)
    }
#undef STAGE
#undef BODY

    // ---- unpack, then merge top-2 across the 4 lane-groups ----
    #pragma unroll
    for (int nt = 0; nt < 4; nt++) {
        float B1 = __uint_as_float(b1k[nt] & MSK7);
        float B2 = __uint_as_float(b2k[nt] & MSK7);
        const int local = 127 - (int)(b1k[nt] & 127u);          // kt*4 + r
        int I = kbase + ((local >> 2) << 4) + lhi * 4 + (local & 3);
        #pragma unroll
        for (int off = 16; off <= 32; off <<= 1) {
            const float o1 = __shfl_xor(B1, off, 64);
            const float o2 = __shfl_xor(B2, off, 64);
            const int   oi = __shfl_xor(I,  off, 64);
            const float nb2 = fmaxf(fminf(B1, o1), fmaxf(B2, o2));
            if (o1 > B1 || (o1 == B1 && oi < I)) { B1 = o1; I = oi; }
            B2 = nb2;
        }
        if (khalf == 1 && lane < 16) {
            const int vloc = vgrp * 64 + nt * 16 + lane;
            red[vloc][0] = B1; red[vloc][1] = B2; red[vloc][2] = __int_as_float(I);
        }
        b1k[nt] = __float_as_uint(B1); b2k[nt] = __float_as_uint(B2);
        if (lane < 16 && khalf == 0) sidx[vgrp * 64 + nt * 16 + lane] = I; // temp park
    }
    __syncthreads();

    if (khalf == 0) {
        #pragma unroll
        for (int nt = 0; nt < 4; nt++) {
            if (lane < 16) {
                const int vloc = vgrp * 64 + nt * 16 + lane;
                const float ob1 = red[vloc][0];
                const float ob2 = red[vloc][1];
                const int   oi  = __float_as_int(red[vloc][2]);
                float B1 = __uint_as_float(b1k[nt]);
                float B2 = __uint_as_float(b2k[nt]);
                int I = sidx[vloc];
                if (ob1 > B1) { B2 = fmaxf(B1, ob2); B1 = ob1; I = oi; }  // kh0 idx < kh1 idx
                else          { B2 = fmaxf(B2, ob1); }
                sidx[vloc] = (B1 - B2 <= SMARGIN) ? -1 : I;
            }
        }
    }
    __syncthreads();

    // ---- epilogue: thread = (vector vloc, dim half dh); writes out + xT ----
    const int vloc = tid & 127;
    const int dh   = tid >> 7;           // 32-dim half
    const int t    = tblk + vloc;
    const int I    = sidx[vloc];
    const int v    = (b << 13) + t;

    float xf[32];
    #pragma unroll
    for (int j = 0; j < 32; j++) xf[j] = xb[((size_t)(dh * 32 + j) << 13) + t];

    if (use_xt) {                        // xT row for the code-reduce
        float4* xtp = (float4*)(xT + (size_t)v * 64 + dh * 32);
        #pragma unroll
        for (int q = 0; q < 8; q++) {
            float4 w; w.x = xf[q*4]; w.y = xf[q*4+1]; w.z = xf[q*4+2]; w.w = xf[q*4+3];
            xtp[q] = w;
        }
    }

    if (I < 0) {
        if (dh == 0) { const int p = atomicAdd(flagcnt, 1); flagids[p] = v; }
    } else {
        if (dh == 0) { idx32[v] = I; atomicAdd(&hcnt[I], 1); }
        const float4* eq4 = (const float4*)(emb + I * DIM + dh * 32);
        #pragma unroll
        for (int q = 0; q < 8; q++) {
            const float4 e4 = eq4[q];
            const int d = dh * 32 + q * 4;
            out[((size_t)b << 19) + ((size_t)(d + 0) << 13) + t] = xf[q*4+0] + (e4.x - xf[q*4+0]);
            out[((size_t)b << 19) + ((size_t)(d + 1) << 13) + t] = xf[q*4+1] + (e4.y - xf[q*4+1]);
            out[((size_t)b << 19) + ((size_t)(d + 2) << 13) + t] = xf[q*4+2] + (e4.z - xf[q*4+2]);
            out[((size_t)b << 19) + ((size_t)(d + 3) << 13) + t] = xf[q*4+3] + (e4.w - xf[q*4+3]);
        }
    }
    __syncthreads();
    #pragma unroll
    for (int q = 0; q < 4; q++) {
        const int c = hcnt[tid + q * 256];
        if (c) atomicAdd(&counts[tid + q * 256], c);
    }
}

// ---- rescan: wave = 4 vectors, e64 direct from L2, zero LDS / barriers ----
__global__ __launch_bounds__(256) void vq_rescan(const float* __restrict__ x,
                                                 const float* __restrict__ emb,
                                                 const double* __restrict__ e64,
                                                 const double* __restrict__ snh64,
                                                 float* __restrict__ out,
                                                 int* __restrict__ idx32,
                                                 int* __restrict__ counts,
                                                 const int* __restrict__ flagcnt,
                                                 const int* __restrict__ flagids) {
    const int tid   = threadIdx.x;
    const int wid   = tid >> 6;          // 4 waves/block
    const int lane  = tid & 63;
    const int cslot = lane >> 2;         // 0..15 code slot
    const int dg    = lane & 3;          // 16-dim group
    const int count = *flagcnt;

    for (int base = blockIdx.x * 16 + wid * 4; base < count; base += gridDim.x * 16) {
        bool act[4]; int vv[4];
        const float* xbp[4];
        double xd[4][16];
        #pragma unroll
        for (int vx = 0; vx < 4; vx++) {
            const int i = base + vx;
            act[vx] = i < count;
            const int v = flagids[act[vx] ? i : 0];
            vv[vx] = v;
            const int b = v >> 13, t = v & (T_ - 1);
            xbp[vx] = x + ((size_t)b << 19) + t;
            #pragma unroll
            for (int j = 0; j < 16; j++)
                xd[vx][j] = act[vx] ? (double)xbp[vx][(size_t)(dg * 16 + j) << 13] : 0.0;
        }

        double best[4] = {-1e300, -1e300, -1e300, -1e300};
        int    bi_[4]  = {0, 0, 0, 0};

        #pragma unroll 4
        for (int cc = 0; cc < 64; cc++) {
            const int k = cc * 16 + cslot;                // in-lane k ascends with cc
            const double* ek = e64 + (size_t)k * DIM + dg * 16;
            const double snh = snh64[k];
            #pragma unroll
            for (int vx = 0; vx < 4; vx++) {
                double a0 = 0.0, a1 = 0.0, a2 = 0.0, a3 = 0.0;
                #pragma unroll
                for (int j = 0; j < 16; j += 4) {
                    a0 = __fma_rn(xd[vx][j + 0], ek[j + 0], a0);
                    a1 = __fma_rn(xd[vx][j + 1], ek[j + 1], a1);
                    a2 = __fma_rn(xd[vx][j + 2], ek[j + 2], a2);
                    a3 = __fma_rn(xd[vx][j + 3], ek[j + 3], a3);
                }
                double a = (a0 + a1) + (a2 + a3);
                a += __shfl_xor(a, 1, 64);
                a += __shfl_xor(a, 2, 64);                // full dot over 4 dim-groups
                const double m = a - snh;
                if (m > best[vx]) { best[vx] = m; bi_[vx] = k; }
            }
        }

        #pragma unroll
        for (int vx = 0; vx < 4; vx++) {
            double bb = best[vx]; int ii = bi_[vx];
            #pragma unroll
            for (int off = 4; off <= 32; off <<= 1) {     // merge across cslots
                const double ob = __shfl_xor(bb, off, 64);
                const int    oi = __shfl_xor(ii, off, 64);
                if (ob > bb || (ob == bb && oi < ii)) { bb = ob; ii = oi; }
            }
            if (act[vx]) {                                // epilogue: lane = dim
                const int v = vv[vx];
                const int b = v >> 13, t = v & (T_ - 1);
                const float xf = xbp[vx][(size_t)lane << 13];
                out[((size_t)b << 19) + ((size_t)lane << 13) + t] =
                    xf + (emb[ii * DIM + lane] - xf);
                if (lane == 0) { idx32[v] = ii; atomicAdd(&counts[ii], 1); }
            }
        }
    }
}

// ---- scatter (scan fused): block-local scan of counts, then counting-sort ----
__global__ __launch_bounds__(256) void vq_scatter(const int* __restrict__ idx32,
                                                  const int* __restrict__ counts,
                                                  int* __restrict__ cnt2,
                                                  int* __restrict__ offsets,
                                                  int* __restrict__ order) {
    __shared__ int soff[K_CODES];
    __shared__ int wsum[4];
    const int tid  = threadIdx.x;
    const int lane = tid & 63;
    const int w    = tid >> 6;

    int c[4]; int tsum = 0;
    #pragma unroll
    for (int j = 0; j < 4; j++) { c[j] = counts[tid * 4 + j]; tsum += c[j]; }
    int s = tsum;
    #pragma unroll
    for (int off = 1; off < 64; off <<= 1) {
        const int o = __shfl_up(s, off, 64);
        if (lane >= off) s += o;
    }
    if (lane == 63) wsum[w] = s;
    __syncthreads();
    int wbase = 0;
    #pragma unroll
    for (int j = 0; j < 4; j++) wbase += (j < w) ? wsum[j] : 0;
    int excl = wbase + s - tsum;
    #pragma unroll
    for (int j = 0; j < 4; j++) { soff[tid * 4 + j] = excl; excl += c[j]; }
    __syncthreads();
    if (blockIdx.x == 0) {               // publish for vq_reduce
        #pragma unroll
        for (int j = 0; j < 4; j++) offsets[tid * 4 + j] = soff[tid * 4 + j];
    }

    const int v = blockIdx.x * 256 + tid;
    const int k = idx32[v];
    const int p = soff[k] + atomicAdd(&cnt2[k], 1);
    order[p] = v;
}

// ---- reduce8: 8 slices per code (straggler / 8); partials to scratch ----
__global__ __launch_bounds__(256) void vq_reduce8(const float* __restrict__ xT,
                                                  const int* __restrict__ order,
                                                  const int* __restrict__ offsets,
                                                  const int* __restrict__ counts,
                                                  float* __restrict__ partials) {
    __shared__ int lv[1024];
    __shared__ float ps[4][64];
    const int k   = blockIdx.x >> 3;
    const int sl  = blockIdx.x & 7;
    const int tid = threadIdx.x;
    const int i4  = tid >> 6;
    const int d   = tid & 63;
    const int cnt = counts[k];
    const int chunk = (cnt + 7) >> 3;
    const int lo = sl * chunk;
    const int hi = min(cnt, lo + chunk);
    const int off = offsets[k] + lo;
    const int n = hi - lo;

    float sum = 0.f;
    for (int base = 0; base < n; base += 1024) {
        const int m = min(1024, n - base);
        __syncthreads();
        for (int i = tid; i < m; i += 256) lv[i] = order[off + base + i];
        __syncthreads();
        float s0 = 0.f, s1 = 0.f;
        int i = i4;
        for (; i + 4 < m; i += 8) {                  // 2-deep to keep loads in flight
            s0 += xT[(size_t)lv[i] * 64 + d];
            s1 += xT[(size_t)lv[i + 4] * 64 + d];
        }
        for (; i < m; i += 4) s0 += xT[(size_t)lv[i] * 64 + d];
        sum += s0 + s1;
    }
    __syncthreads();
    ps[i4][d] = sum;
    __syncthreads();
    if (i4 == 0)
        partials[(((size_t)sl << 10) + k) * 64 + d] = ps[0][d] + ps[1][d] + ps[2][d] + ps[3][d];
}

// ---- fin: sum 8 partials, divide by cluster_size ----
__global__ __launch_bounds__(64) void vq_fin(const float* __restrict__ partials,
                                             const int* __restrict__ counts,
                                             float* __restrict__ newemb) {
    const int k = blockIdx.x;
    const int d = threadIdx.x;
    float tot = 0.f;
    #pragma unroll
    for (int sl = 0; sl < 8; sl++) tot += partials[(((size_t)sl << 10) + k) * 64 + d];
    const float c = (float)counts[k];
    const float cluster = (c + EPSF) / (131072.0f + 1024.0f * EPSF) * 131072.0f;
    newemb[k * DIM + d] = tot / cluster;
}

// ---- reduce (fallback, ws too small for partials): block per code ----
__global__ __launch_bounds__(256) void vq_reduce(const float* __restrict__ x,
                                                 const float* __restrict__ xT,
                                                 const int* __restrict__ order,
                                                 const int* __restrict__ offsets,
                                                 const int* __restrict__ counts,
                                                 float* __restrict__ newemb,
                                                 int use_xt) {
    __shared__ int lv[1024];
    __shared__ float ps[4][64];
    const int k = blockIdx.x;
    const int tid = threadIdx.x;
    const int i4 = tid >> 6;
    const int d = tid & 63;
    const int off = offsets[k];
    const int cnt = counts[k];
    float sum = 0.f;
    for (int base = 0; base < cnt; base += 1024) {
        const int m = min(1024, cnt - base);
        __syncthreads();
        for (int i = tid; i < m; i += 256) lv[i] = order[off + base + i];
        __syncthreads();
        if (use_xt) {
            for (int i = i4; i < m; i += 4) sum += xT[(size_t)lv[i] * 64 + d];
        } else {
            for (int i = i4; i < m; i += 4) {
                const int v = lv[i];
                sum += x[((size_t)(v >> 13) << 19) + ((size_t)d << 13) + (v & (T_ - 1))];
            }
        }
    }
    __syncthreads();
    ps[i4][d] = sum;
    __syncthreads();
    if (i4 == 0) {
        const float tot = ps[0][d] + ps[1][d] + ps[2][d] + ps[3][d];
        const float c = (float)cnt;
        const float cluster = (c + EPSF) / (131072.0f + 1024.0f * EPSF) * 131072.0f;
        newemb[k * DIM + d] = tot / cluster;
    }
}

extern "C" void kernel_launch(void* const* d_in, const int* in_sizes, int n_in,
                              void* d_out, int out_size, void* d_ws, size_t ws_size,
                              hipStream_t stream) {
    const float* x   = (const float*)d_in[0];
    const float* emb = (const float*)d_in[1];

    char* ws = (char*)d_ws;
    double*         e64     = (double*)(ws);                  //  524288 B
    double*         snh64   = (double*)(ws + 524288);         //    8192 B
    float*          snb32   = (float*)(ws + 532480);          //    4096 B
    unsigned short* ehib    = (unsigned short*)(ws + 536576); //  131072 B
    unsigned short* elob    = (unsigned short*)(ws + 667648); //  131072 B
    int*            idx32   = (int*)(ws + 798720);            //  524288 B
    int*            order   = (int*)(ws + 1323008);           //  524288 B
    int*            counts  = (int*)(ws + 1847296);           //    4096 B
    int*            flagcnt = (int*)(ws + 1851392);           //      64 B
    int*            offsets = (int*)(ws + 1851456);           //    4096 B
    int*            cnt2    = (int*)(ws + 1855552);           //    4096 B
    int*            flagids = (int*)(ws + 1859648);           //  524288 B
    float*          xT      = (float*)(ws + 2383936);         // 33554432 B (optional)
    float*          part8   = (float*)(ws + 35938368);        //  2097152 B (optional)
    const int use_xt = (ws_size >= (size_t)2383936 + 33554432) ? 1 : 0;
    const int use_p8 = (use_xt && ws_size >= (size_t)35938368 + 2097152) ? 1 : 0;

    float* out    = (float*)d_out;
    float* newemb = out + (size_t)B_ * DIM * T_;

    vq_prep<<<K_CODES, 64, 0, stream>>>(emb, e64, snh64, snb32, ehib, elob,
                                        counts, cnt2, flagcnt);
    vq_screen<<<N_ / 128, 256, 0, stream>>>(x, ehib, elob, snb32, emb, out, xT, idx32,
                                            counts, flagcnt, flagids, use_xt);
    vq_rescan<<<512, 256, 0, stream>>>(x, emb, e64, snh64, out, idx32, counts,
                                       flagcnt, flagids);
    vq_scatter<<<N_ / 256, 256, 0, stream>>>(idx32, counts, cnt2, offsets, order);
    if (use_p8) {
        vq_reduce8<<<K_CODES * 8, 256, 0, stream>>>(xT, order, offsets, counts, part8);
        vq_fin<<<K_CODES, 64, 0, stream>>>(part8, counts, newemb);
    } else {
        vq_reduce<<<K_CODES, 256, 0, stream>>>(x, xT, order, offsets, counts, newemb, use_xt);
    }
}

// Round 19
// 168.678 us; speedup vs baseline: 1.5606x; 1.2531x over previous
//
#include <hip/hip_runtime.h>

#define K_CODES 1024
#define DIM 64
#define B_ 16
#define T_ 8192
#define N_ (B_*T_)          // 131072 vectors
#define EPSF 1e-5f
#define SMARGIN 5e-4f       // exact-float margin; > 2x the 7-bit key quantum 2.44e-4
#define MSK7 0xFFFFFF80u

typedef __attribute__((ext_vector_type(8))) short short8;   // 8 bf16 = 4 VGPR
typedef __attribute__((ext_vector_type(4))) float f32x4;

typedef __attribute__((address_space(1))) unsigned char g1_t;   // global
typedef __attribute__((address_space(3))) unsigned char l3_t;   // LDS

__device__ __forceinline__ unsigned bf16_rne(float f) {
    unsigned u = __float_as_uint(f);
    return (u + 0x7fffu + ((u >> 16) & 1u)) >> 16;
}
__device__ __forceinline__ unsigned umx(unsigned a, unsigned b) { return a > b ? a : b; }
__device__ __forceinline__ unsigned umn(unsigned a, unsigned b) { return a < b ? a : b; }

// ---- prep: e -> bf16 hi/lo tables, fp64 table, norms; zero accumulators ----
__global__ __launch_bounds__(64) void vq_prep(const float* __restrict__ emb,
                                              double* __restrict__ e64,
                                              double* __restrict__ snh64,
                                              float* __restrict__ snb32,
                                              unsigned short* __restrict__ ehib,
                                              unsigned short* __restrict__ elob,
                                              int* __restrict__ counts,
                                              int* __restrict__ cnt2,
                                              int* __restrict__ flagcnt) {
    const int k = blockIdx.x;
    const int d = threadIdx.x;
    if (d == 0) counts[k] = 0;
    if (d == 1) cnt2[k] = 0;
    if (k == 0 && d == 2) *flagcnt = 0;

    const float ef = emb[k * DIM + d];
    const unsigned rh = bf16_rne(ef);
    const float hif = __uint_as_float(rh << 16);
    const float lof = ef - hif;                   // exact (Sterbenz)
    const unsigned rl = bf16_rne(lof);
    ehib[k * DIM + d] = (unsigned short)rh;
    elob[k * DIM + d] = (unsigned short)rl;

    const double ed = (double)ef;
    e64[k * DIM + d] = ed;
    double s = ed * ed;
    #pragma unroll
    for (int off = 32; off; off >>= 1) s += __shfl_down(s, off, 64);
    if (d == 0) {
        snh64[k] = 0.5 * s;
        snb32[k] = (float)(16.0 - 0.5 * s);   // +16 bias: scores in (8,24), positive
    }
}

// ---- screen: split-bf16 MFMA, packed-key top-2, LDS-staged e (dbuf+swz) ----
// block = 4 waves = 2 vgrp(64 vec) x 2 khalf(512 codes); 128 vec/block; grid 1024.
__global__ __launch_bounds__(256) void vq_screen(const float* __restrict__ x,
                                                 const unsigned short* __restrict__ ehib,
                                                 const unsigned short* __restrict__ elob,
                                                 const float* __restrict__ snb32,
                                                 const float* __restrict__ emb,
                                                 float* __restrict__ out,
                                                 float* __restrict__ xT,
                                                 int* __restrict__ idx32,
                                                 int* __restrict__ counts,
                                                 int* __restrict__ flagcnt,
                                                 int* __restrict__ flagids,
                                                 int use_xt) {
    __shared__ unsigned short stg[2][2][2048]; // [khalf][buf][hi 1024hw | lo 1024hw]
    __shared__ float red[128][4];              // khalf=1: b1, b2, idx-bits
    __shared__ int sidx[128];                  // merged: code index, or -1 = flagged
    __shared__ int hcnt[K_CODES];              // per-block histogram

    const int tid   = threadIdx.x;
    const int wid   = tid >> 6;
    const int lane  = tid & 63;
    const int vgrp  = wid & 1;
    const int khalf = wid >> 1;
    const int ln15  = lane & 15;
    const int lhi   = lane >> 4;               // 0..3

    #pragma unroll
    for (int q = 0; q < 4; q++) hcnt[tid + q * 256] = 0;

    const int blk  = blockIdx.x;               // 1024 blocks x 128 vectors
    const int b    = blk >> 6;
    const int tblk = (blk & 63) << 7;
    const int t0   = tblk + vgrp * 64;
    const float* xb = x + ((size_t)b << 19);

    // ---- x B-fragments (hi/lo), register-resident ----
    short8 xbh[4][2], xbl[4][2];
    #pragma unroll
    for (int nt = 0; nt < 4; nt++) {
        const int t = t0 + nt * 16 + ln15;
        #pragma unroll
        for (int s = 0; s < 2; s++) {
            #pragma unroll
            for (int j = 0; j < 8; j++) {
                const int d = s * 32 + lhi * 8 + j;
                const float xf = xb[((size_t)d << 13) + t];
                const unsigned rh = bf16_rne(xf);
                const float hif = __uint_as_float(rh << 16);
                const unsigned rl = bf16_rne(xf - hif);
                xbh[nt][s][j] = (short)rh;
                xbl[nt][s][j] = (short)rl;
            }
        }
    }

    // staging: pre-swizzled source byte offset (G4 swizzle, rule 21)
    const int srow = lane >> 3;
    const int soff = (srow << 7) + (((lane & 7) ^ srow) << 4);
    const int rx = ln15 & 7;
    const int c0 = (lhi ^ rx) << 3;
    const int c1 = ((4 + lhi) ^ rx) << 3;
    const int rbase = ln15 * 64;

    const int kbase = khalf << 9;

#define STAGE(BUF, KT) { \
    const size_t tb_ = (size_t)(kbase + ((KT) << 4)) * DIM; \
    if (vgrp == 0) { \
        const unsigned char* g_ = (const unsigned char*)(ehib + tb_) + soff; \
        unsigned short* l_ = &stg[khalf][BUF][0]; \
        __builtin_amdgcn_global_load_lds((const g1_t*)g_,          (l3_t*)l_,          16, 0, 0); \
        __builtin_amdgcn_global_load_lds((const g1_t*)(g_ + 1024), (l3_t*)(l_ + 512),  16, 0, 0); \
    } else { \
        const unsigned char* g_ = (const unsigned char*)(elob + tb_) + soff; \
        unsigned short* l_ = &stg[khalf][BUF][1024]; \
        __builtin_amdgcn_global_load_lds((const g1_t*)g_,          (l3_t*)l_,          16, 0, 0); \
        __builtin_amdgcn_global_load_lds((const g1_t*)(g_ + 1024), (l3_t*)(l_ + 512),  16, 0, 0); \
    } \
}

    // packed keys: high 25 bits = positive-score float bits, low 7 = 127-local
    unsigned b1k[4] = {0, 0, 0, 0}, b2k[4] = {0, 0, 0, 0};

#define BODY(BUF, KT, DOPRE, NKT) { \
    if (DOPRE) STAGE((BUF) ^ 1, NKT) \
    const unsigned short* lb = &stg[khalf][BUF][0]; \
    const short8 ah0 = *(const short8*)(lb + rbase + c0); \
    const short8 ah1 = *(const short8*)(lb + rbase + c1); \
    const short8 al0 = *(const short8*)(lb + 1024 + rbase + c0); \
    const short8 al1 = *(const short8*)(lb + 1024 + rbase + c1); \
    const int k0_ = kbase + ((KT) << 4); \
    const f32x4 bias = *(const f32x4*)(snb32 + k0_ + lhi * 4); \
    const unsigned revb = 127u - (unsigned)((KT) << 2); \
    _Pragma("unroll") \
    for (int nt = 0; nt < 4; nt++) { \
        f32x4 acc = bias; \
        acc = __builtin_amdgcn_mfma_f32_16x16x32_bf16(ah0, xbh[nt][0], acc, 0, 0, 0); \
        acc = __builtin_amdgcn_mfma_f32_16x16x32_bf16(ah1, xbh[nt][1], acc, 0, 0, 0); \
        acc = __builtin_amdgcn_mfma_f32_16x16x32_bf16(ah0, xbl[nt][0], acc, 0, 0, 0); \
        acc = __builtin_amdgcn_mfma_f32_16x16x32_bf16(ah1, xbl[nt][1], acc, 0, 0, 0); \
        acc = __builtin_amdgcn_mfma_f32_16x16x32_bf16(al0, xbh[nt][0], acc, 0, 0, 0); \
        acc = __builtin_amdgcn_mfma_f32_16x16x32_bf16(al1, xbh[nt][1], acc, 0, 0, 0); \
        _Pragma("unroll") \
        for (int r = 0; r < 4; r++) { \
            const unsigned key = (__float_as_uint(acc[r]) & MSK7) | (revb - r); \
            b2k[nt] = umx(b2k[nt], umn(b1k[nt], key)); \
            b1k[nt] = umx(b1k[nt], key); \
        } \
    } \
    __syncthreads(); \
}

    STAGE(0, 0)
    __syncthreads();
    #pragma unroll 1
    for (int kt2 = 0; kt2 < 32; kt2 += 2) {
        BODY(0, kt2, 1, kt2 + 1)
        BODY(1, kt2 + 1, (kt2 < 30), kt2 + 2)
    }
#undef STAGE
#undef BODY

    // ---- unpack, then merge top-2 across the 4 lane-groups ----
    #pragma unroll
    for (int nt = 0; nt < 4; nt++) {
        float B1 = __uint_as_float(b1k[nt] & MSK7);
        float B2 = __uint_as_float(b2k[nt] & MSK7);
        const int local = 127 - (int)(b1k[nt] & 127u);          // kt*4 + r
        int I = kbase + ((local >> 2) << 4) + lhi * 4 + (local & 3);
        #pragma unroll
        for (int off = 16; off <= 32; off <<= 1) {
            const float o1 = __shfl_xor(B1, off, 64);
            const float o2 = __shfl_xor(B2, off, 64);
            const int   oi = __shfl_xor(I,  off, 64);
            const float nb2 = fmaxf(fminf(B1, o1), fmaxf(B2, o2));
            if (o1 > B1 || (o1 == B1 && oi < I)) { B1 = o1; I = oi; }
            B2 = nb2;
        }
        if (khalf == 1 && lane < 16) {
            const int vloc = vgrp * 64 + nt * 16 + lane;
            red[vloc][0] = B1; red[vloc][1] = B2; red[vloc][2] = __int_as_float(I);
        }
        b1k[nt] = __float_as_uint(B1); b2k[nt] = __float_as_uint(B2);
        if (lane < 16 && khalf == 0) sidx[vgrp * 64 + nt * 16 + lane] = I; // temp park
    }
    __syncthreads();

    if (khalf == 0) {
        #pragma unroll
        for (int nt = 0; nt < 4; nt++) {
            if (lane < 16) {
                const int vloc = vgrp * 64 + nt * 16 + lane;
                const float ob1 = red[vloc][0];
                const float ob2 = red[vloc][1];
                const int   oi  = __float_as_int(red[vloc][2]);
                float B1 = __uint_as_float(b1k[nt]);
                float B2 = __uint_as_float(b2k[nt]);
                int I = sidx[vloc];
                if (ob1 > B1) { B2 = fmaxf(B1, ob2); B1 = ob1; I = oi; }  // kh0 idx < kh1 idx
                else          { B2 = fmaxf(B2, ob1); }
                sidx[vloc] = (B1 - B2 <= SMARGIN) ? -1 : I;
            }
        }
    }
    __syncthreads();

    // ---- epilogue: thread = (vector vloc, dim half dh); writes out + xT ----
    const int vloc = tid & 127;
    const int dh   = tid >> 7;           // 32-dim half
    const int t    = tblk + vloc;
    const int I    = sidx[vloc];
    const int v    = (b << 13) + t;

    float xf[32];
    #pragma unroll
    for (int j = 0; j < 32; j++) xf[j] = xb[((size_t)(dh * 32 + j) << 13) + t];

    if (use_xt) {                        // xT row for the code-reduce
        float4* xtp = (float4*)(xT + (size_t)v * 64 + dh * 32);
        #pragma unroll
        for (int q = 0; q < 8; q++) {
            float4 w; w.x = xf[q*4]; w.y = xf[q*4+1]; w.z = xf[q*4+2]; w.w = xf[q*4+3];
            xtp[q] = w;
        }
    }

    if (I < 0) {
        if (dh == 0) { const int p = atomicAdd(flagcnt, 1); flagids[p] = v; }
    } else {
        if (dh == 0) { idx32[v] = I; atomicAdd(&hcnt[I], 1); }
        const float4* eq4 = (const float4*)(emb + I * DIM + dh * 32);
        #pragma unroll
        for (int q = 0; q < 8; q++) {
            const float4 e4 = eq4[q];
            const int d = dh * 32 + q * 4;
            out[((size_t)b << 19) + ((size_t)(d + 0) << 13) + t] = xf[q*4+0] + (e4.x - xf[q*4+0]);
            out[((size_t)b << 19) + ((size_t)(d + 1) << 13) + t] = xf[q*4+1] + (e4.y - xf[q*4+1]);
            out[((size_t)b << 19) + ((size_t)(d + 2) << 13) + t] = xf[q*4+2] + (e4.z - xf[q*4+2]);
            out[((size_t)b << 19) + ((size_t)(d + 3) << 13) + t] = xf[q*4+3] + (e4.w - xf[q*4+3]);
        }
    }
    __syncthreads();
    #pragma unroll
    for (int q = 0; q < 4; q++) {
        const int c = hcnt[tid + q * 256];
        if (c) atomicAdd(&counts[tid + q * 256], c);
    }
}

// ---- rescan: block = 4 waves x SAME 4 vectors, k-split x4; exact fp64 ----
__global__ __launch_bounds__(256) void vq_rescan(const float* __restrict__ x,
                                                 const float* __restrict__ emb,
                                                 const double* __restrict__ e64,
                                                 const double* __restrict__ snh64,
                                                 float* __restrict__ out,
                                                 int* __restrict__ idx32,
                                                 int* __restrict__ counts,
                                                 const int* __restrict__ flagcnt,
                                                 const int* __restrict__ flagids) {
    __shared__ double rb[4][4];          // [kquarter][vx] wave best
    __shared__ int    ri[4][4];
    __shared__ int    rf[4];             // merged idx per vx
    const int tid   = threadIdx.x;
    const int wid   = tid >> 6;          // k-quarter (0..3)
    const int lane  = tid & 63;
    const int cslot = lane >> 2;         // 0..15 code slot
    const int dg    = lane & 3;          // 16-dim group
    const int count = *flagcnt;

    for (int base = blockIdx.x * 4; base < count; base += gridDim.x * 4) {
        bool act[4]; int vv[4];
        const float* xbp[4];
        double xd[4][16];
        #pragma unroll
        for (int vx = 0; vx < 4; vx++) {
            const int i = base + vx;
            act[vx] = i < count;
            const int v = flagids[act[vx] ? i : 0];
            vv[vx] = v;
            const int b = v >> 13, t = v & (T_ - 1);
            xbp[vx] = x + ((size_t)b << 19) + t;
            #pragma unroll
            for (int j = 0; j < 16; j++)
                xd[vx][j] = act[vx] ? (double)xbp[vx][(size_t)(dg * 16 + j) << 13] : 0.0;
        }

        double best[4] = {-1e300, -1e300, -1e300, -1e300};
        int    bi_[4]  = {0, 0, 0, 0};
        const int kq = wid << 8;         // this wave's 256 codes

        #pragma unroll 4
        for (int cc = 0; cc < 16; cc++) {
            const int k = kq + cc * 16 + cslot;           // in-lane k ascends with cc
            const double* ek = e64 + (size_t)k * DIM + dg * 16;
            const double snh = snh64[k];
            #pragma unroll
            for (int vx = 0; vx < 4; vx++) {
                double a0 = 0.0, a1 = 0.0, a2 = 0.0, a3 = 0.0;
                #pragma unroll
                for (int j = 0; j < 16; j += 4) {
                    a0 = __fma_rn(xd[vx][j + 0], ek[j + 0], a0);
                    a1 = __fma_rn(xd[vx][j + 1], ek[j + 1], a1);
                    a2 = __fma_rn(xd[vx][j + 2], ek[j + 2], a2);
                    a3 = __fma_rn(xd[vx][j + 3], ek[j + 3], a3);
                }
                double a = (a0 + a1) + (a2 + a3);
                a += __shfl_xor(a, 1, 64);
                a += __shfl_xor(a, 2, 64);                // full dot over 4 dim-groups
                const double m = a - snh;
                if (m > best[vx]) { best[vx] = m; bi_[vx] = k; }
            }
        }

        #pragma unroll
        for (int vx = 0; vx < 4; vx++) {
            double bb = best[vx]; int ii = bi_[vx];
            #pragma unroll
            for (int off = 4; off <= 32; off <<= 1) {     // merge across cslots
                const double ob = __shfl_xor(bb, off, 64);
                const int    oi = __shfl_xor(ii, off, 64);
                if (ob > bb || (ob == bb && oi < ii)) { bb = ob; ii = oi; }
            }
            if (lane == 0) { rb[wid][vx] = bb; ri[wid][vx] = ii; }
        }
        __syncthreads();
        if (tid < 4) {                    // thread vx: merge quarters ascending
            double bb = rb[0][tid]; int ii = ri[0][tid];
            #pragma unroll
            for (int w = 1; w < 4; w++) {
                if (rb[w][tid] > bb) { bb = rb[w][tid]; ii = ri[w][tid]; }  // strict >: lower k wins ties
            }
            rf[tid] = ii;
        }
        __syncthreads();

        {   // epilogue: wave wid handles vector wid; lane = dim
            const int vx = wid;
            if (act[vx]) {
                const int v = vv[vx];
                const int b = v >> 13, t = v & (T_ - 1);
                const int I = rf[vx];
                const float xf = xbp[vx][(size_t)lane << 13];
                out[((size_t)b << 19) + ((size_t)lane << 13) + t] =
                    xf + (emb[I * DIM + lane] - xf);
                if (lane == 0) { idx32[v] = I; atomicAdd(&counts[I], 1); }
            }
        }
        __syncthreads();                  // protect rb/ri/rf for next iteration
    }
}

// ---- scatter (scan fused, 1024 thr): scan counts, then counting-sort ----
__global__ __launch_bounds__(1024) void vq_scatter(const int* __restrict__ idx32,
                                                   const int* __restrict__ counts,
                                                   int* __restrict__ cnt2,
                                                   int* __restrict__ offsets,
                                                   int* __restrict__ order) {
    __shared__ int soff[K_CODES];
    __shared__ int wtot[16];
    const int tid  = threadIdx.x;
    const int lane = tid & 63;
    const int w    = tid >> 6;

    const int c = counts[tid];
    int s = c;
    #pragma unroll
    for (int off = 1; off < 64; off <<= 1) {
        const int o = __shfl_up(s, off, 64);
        if (lane >= off) s += o;
    }
    if (lane == 63) wtot[w] = s;
    __syncthreads();
    if (tid < 16) {
        int ws_ = wtot[tid];
        #pragma unroll
        for (int off = 1; off < 16; off <<= 1) {
            const int o = __shfl_up(ws_, off, 64);
            if (tid >= off) ws_ += o;
        }
        wtot[tid] = ws_;                 // inclusive scan of wave totals
    }
    __syncthreads();
    const int wbase = (w > 0) ? wtot[w - 1] : 0;
    soff[tid] = wbase + s - c;           // exclusive prefix
    __syncthreads();
    if (blockIdx.x == 0) offsets[tid] = soff[tid];   // publish for vq_reduce8

    const int v = blockIdx.x * 1024 + tid;
    const int k = idx32[v];
    const int p = soff[k] + atomicAdd(&cnt2[k], 1);
    order[p] = v;
}

// ---- reduce8: 8 slices per code; 4-deep gather; partials to scratch ----
__global__ __launch_bounds__(256) void vq_reduce8(const float* __restrict__ xT,
                                                  const int* __restrict__ order,
                                                  const int* __restrict__ offsets,
                                                  const int* __restrict__ counts,
                                                  float* __restrict__ partials) {
    __shared__ int lv[1024];
    __shared__ float ps[4][64];
    const int k   = blockIdx.x >> 3;
    const int sl  = blockIdx.x & 7;
    const int tid = threadIdx.x;
    const int i4  = tid >> 6;
    const int d   = tid & 63;
    const int cnt = counts[k];
    const int chunk = (cnt + 7) >> 3;
    const int lo = sl * chunk;
    const int hi = min(cnt, lo + chunk);
    const int off = offsets[k] + lo;
    const int n = hi - lo;

    float sum = 0.f;
    for (int base = 0; base < n; base += 1024) {
        const int m = min(1024, n - base);
        __syncthreads();
        for (int i = tid; i < m; i += 256) lv[i] = order[off + base + i];
        __syncthreads();
        float s0 = 0.f, s1 = 0.f, s2 = 0.f, s3 = 0.f;
        int i = i4;
        for (; i + 12 < m; i += 16) {                // 4-deep to keep loads in flight
            s0 += xT[(size_t)lv[i] * 64 + d];
            s1 += xT[(size_t)lv[i + 4] * 64 + d];
            s2 += xT[(size_t)lv[i + 8] * 64 + d];
            s3 += xT[(size_t)lv[i + 12] * 64 + d];
        }
        for (; i < m; i += 4) s0 += xT[(size_t)lv[i] * 64 + d];
        sum += (s0 + s1) + (s2 + s3);
    }
    __syncthreads();
    ps[i4][d] = sum;
    __syncthreads();
    if (i4 == 0)
        partials[(((size_t)sl << 10) + k) * 64 + d] = ps[0][d] + ps[1][d] + ps[2][d] + ps[3][d];
}

// ---- fin: sum 8 partials, divide by cluster_size ----
__global__ __launch_bounds__(64) void vq_fin(const float* __restrict__ partials,
                                             const int* __restrict__ counts,
                                             float* __restrict__ newemb) {
    const int k = blockIdx.x;
    const int d = threadIdx.x;
    float tot = 0.f;
    #pragma unroll
    for (int sl = 0; sl < 8; sl++) tot += partials[(((size_t)sl << 10) + k) * 64 + d];
    const float c = (float)counts[k];
    const float cluster = (c + EPSF) / (131072.0f + 1024.0f * EPSF) * 131072.0f;
    newemb[k * DIM + d] = tot / cluster;
}

// ---- reduce (fallback, ws too small for partials): block per code ----
__global__ __launch_bounds__(256) void vq_reduce(const float* __restrict__ x,
                                                 const float* __restrict__ xT,
                                                 const int* __restrict__ order,
                                                 const int* __restrict__ offsets,
                                                 const int* __restrict__ counts,
                                                 float* __restrict__ newemb,
                                                 int use_xt) {
    __shared__ int lv[1024];
    __shared__ float ps[4][64];
    const int k = blockIdx.x;
    const int tid = threadIdx.x;
    const int i4 = tid >> 6;
    const int d = tid & 63;
    const int off = offsets[k];
    const int cnt = counts[k];
    float sum = 0.f;
    for (int base = 0; base < cnt; base += 1024) {
        const int m = min(1024, cnt - base);
        __syncthreads();
        for (int i = tid; i < m; i += 256) lv[i] = order[off + base + i];
        __syncthreads();
        if (use_xt) {
            for (int i = i4; i < m; i += 4) sum += xT[(size_t)lv[i] * 64 + d];
        } else {
            for (int i = i4; i < m; i += 4) {
                const int v = lv[i];
                sum += x[((size_t)(v >> 13) << 19) + ((size_t)d << 13) + (v & (T_ - 1))];
            }
        }
    }
    __syncthreads();
    ps[i4][d] = sum;
    __syncthreads();
    if (i4 == 0) {
        const float tot = ps[0][d] + ps[1][d] + ps[2][d] + ps[3][d];
        const float c = (float)cnt;
        const float cluster = (c + EPSF) / (131072.0f + 1024.0f * EPSF) * 131072.0f;
        newemb[k * DIM + d] = tot / cluster;
    }
}

extern "C" void kernel_launch(void* const* d_in, const int* in_sizes, int n_in,
                              void* d_out, int out_size, void* d_ws, size_t ws_size,
                              hipStream_t stream) {
    const float* x   = (const float*)d_in[0];
    const float* emb = (const float*)d_in[1];

    char* ws = (char*)d_ws;
    double*         e64     = (double*)(ws);                  //  524288 B
    double*         snh64   = (double*)(ws + 524288);         //    8192 B
    float*          snb32   = (float*)(ws + 532480);          //    4096 B
    unsigned short* ehib    = (unsigned short*)(ws + 536576); //  131072 B
    unsigned short* elob    = (unsigned short*)(ws + 667648); //  131072 B
    int*            idx32   = (int*)(ws + 798720);            //  524288 B
    int*            order   = (int*)(ws + 1323008);           //  524288 B
    int*            counts  = (int*)(ws + 1847296);           //    4096 B
    int*            flagcnt = (int*)(ws + 1851392);           //      64 B
    int*            offsets = (int*)(ws + 1851456);           //    4096 B
    int*            cnt2    = (int*)(ws + 1855552);           //    4096 B
    int*            flagids = (int*)(ws + 1859648);           //  524288 B
    float*          xT      = (float*)(ws + 2383936);         // 33554432 B (optional)
    float*          part8   = (float*)(ws + 35938368);        //  2097152 B (optional)
    const int use_xt = (ws_size >= (size_t)2383936 + 33554432) ? 1 : 0;
    const int use_p8 = (use_xt && ws_size >= (size_t)35938368 + 2097152) ? 1 : 0;

    float* out    = (float*)d_out;
    float* newemb = out + (size_t)B_ * DIM * T_;

    vq_prep<<<K_CODES, 64, 0, stream>>>(emb, e64, snh64, snb32, ehib, elob,
                                        counts, cnt2, flagcnt);
    vq_screen<<<N_ / 128, 256, 0, stream>>>(x, ehib, elob, snb32, emb, out, xT, idx32,
                                            counts, flagcnt, flagids, use_xt);
    vq_rescan<<<2048, 256, 0, stream>>>(x, emb, e64, snh64, out, idx32, counts,
                                        flagcnt, flagids);
    vq_scatter<<<N_ / 1024, 1024, 0, stream>>>(idx32, counts, cnt2, offsets, order);
    if (use_p8) {
        vq_reduce8<<<K_CODES * 8, 256, 0, stream>>>(xT, order, offsets, counts, part8);
        vq_fin<<<K_CODES, 64, 0, stream>>>(part8, counts, newemb);
    } else {
        vq_reduce<<<K_CODES, 256, 0, stream>>>(x, xT, order, offsets, counts, newemb, use_xt);
    }
}

// Round 20
// 163.677 us; speedup vs baseline: 1.6083x; 1.0306x over previous
//
#include <hip/hip_runtime.h>

#define K_CODES 1024
#define DIM 64
#define B_ 16
#define T_ 8192
#define N_ (B_*T_)          // 131072 vectors
#define EPSF 1e-5f
#define SMARGIN 5e-4f       // exact-float margin; > 2x the 7-bit key quantum 2.44e-4
#define MSK7 0xFFFFFF80u

typedef __attribute__((ext_vector_type(8))) short short8;   // 8 bf16 = 4 VGPR
typedef __attribute__((ext_vector_type(4))) float f32x4;

typedef __attribute__((address_space(1))) unsigned char g1_t;   // global
typedef __attribute__((address_space(3))) unsigned char l3_t;   // LDS

__device__ __forceinline__ unsigned bf16_rne(float f) {
    unsigned u = __float_as_uint(f);
    return (u + 0x7fffu + ((u >> 16) & 1u)) >> 16;
}
__device__ __forceinline__ unsigned umx(unsigned a, unsigned b) { return a > b ? a : b; }
__device__ __forceinline__ unsigned umn(unsigned a, unsigned b) { return a < b ? a : b; }

// ---- prep: e -> bf16 hi/lo tables, fp64 table, norms; zero accumulators ----
__global__ __launch_bounds__(64) void vq_prep(const float* __restrict__ emb,
                                              double* __restrict__ e64,
                                              double* __restrict__ snh64,
                                              float* __restrict__ snb32,
                                              unsigned short* __restrict__ ehib,
                                              unsigned short* __restrict__ elob,
                                              int* __restrict__ counts,
                                              int* __restrict__ cnt2,
                                              int* __restrict__ flagcnt) {
    const int k = blockIdx.x;
    const int d = threadIdx.x;
    if (d == 0) counts[k] = 0;
    if (d == 1) cnt2[k] = 0;
    if (k == 0 && d == 2) *flagcnt = 0;

    const float ef = emb[k * DIM + d];
    const unsigned rh = bf16_rne(ef);
    const float hif = __uint_as_float(rh << 16);
    const float lof = ef - hif;                   // exact (Sterbenz)
    const unsigned rl = bf16_rne(lof);
    ehib[k * DIM + d] = (unsigned short)rh;
    elob[k * DIM + d] = (unsigned short)rl;

    const double ed = (double)ef;
    e64[k * DIM + d] = ed;
    double s = ed * ed;
    #pragma unroll
    for (int off = 32; off; off >>= 1) s += __shfl_down(s, off, 64);
    if (d == 0) {
        snh64[k] = 0.5 * s;
        snb32[k] = (float)(16.0 - 0.5 * s);   // +16 bias: scores in (8,24), positive
    }
}

// ---- screen: split-bf16 MFMA, packed-key top-2, T3/T4 pipelined staging ----
// block = 4 waves = 2 vgrp(64 vec) x 2 khalf(512 codes); 128 vec/block; grid 1024.
// Triple-buffered shared e-staging, counted vmcnt(2), raw s_barrier (no drain).
__global__ __launch_bounds__(256) void vq_screen(const float* __restrict__ x,
                                                 const unsigned short* __restrict__ ehib,
                                                 const unsigned short* __restrict__ elob,
                                                 const float* __restrict__ snb32,
                                                 const float* __restrict__ emb,
                                                 float* __restrict__ out,
                                                 float* __restrict__ xT,
                                                 int* __restrict__ idx32,
                                                 int* __restrict__ counts,
                                                 int* __restrict__ flagcnt,
                                                 int* __restrict__ flagids,
                                                 int use_xt) {
    __shared__ unsigned short stg[2][3][2048]; // [khalf][buf][hi 1024hw | lo 1024hw]
    __shared__ float snl[K_CODES];             // biased norms in LDS (loop has no VMEM)
    __shared__ float red[128][4];              // khalf=1: b1, b2, idx-bits
    __shared__ int sidx[128];                  // merged: code index, or -1 = flagged
    __shared__ int hcnt[K_CODES];              // per-block histogram

    const int tid   = threadIdx.x;
    const int wid   = tid >> 6;
    const int lane  = tid & 63;
    const int vgrp  = wid & 1;
    const int khalf = wid >> 1;
    const int ln15  = lane & 15;
    const int lhi   = lane >> 4;               // 0..3

    #pragma unroll
    for (int q = 0; q < 4; q++) hcnt[tid + q * 256] = 0;

    const int blk  = blockIdx.x;               // 1024 blocks x 128 vectors
    const int b    = blk >> 6;
    const int tblk = (blk & 63) << 7;
    const int t0   = tblk + vgrp * 64;
    const float* xb = x + ((size_t)b << 19);

    // ---- stage biased norms to LDS (vgrp0 waves only; oldest in vm queue) ----
    if (vgrp == 0) {
        const unsigned char* gs = (const unsigned char*)(snb32 + (khalf << 9));
        unsigned char* ls = (unsigned char*)&snl[khalf << 9];
        __builtin_amdgcn_global_load_lds((const g1_t*)(gs + lane * 16),        (l3_t*)ls,          16, 0, 0);
        __builtin_amdgcn_global_load_lds((const g1_t*)(gs + 1024 + lane * 16), (l3_t*)(ls + 1024), 16, 0, 0);
    }

    // ---- x B-fragments (hi/lo), register-resident ----
    short8 xbh[4][2], xbl[4][2];
    #pragma unroll
    for (int nt = 0; nt < 4; nt++) {
        const int t = t0 + nt * 16 + ln15;
        #pragma unroll
        for (int s = 0; s < 2; s++) {
            #pragma unroll
            for (int j = 0; j < 8; j++) {
                const int d = s * 32 + lhi * 8 + j;
                const float xf = xb[((size_t)d << 13) + t];
                const unsigned rh = bf16_rne(xf);
                const float hif = __uint_as_float(rh << 16);
                const unsigned rl = bf16_rne(xf - hif);
                xbh[nt][s][j] = (short)rh;
                xbl[nt][s][j] = (short)rl;
            }
        }
    }

    // staging: pre-swizzled source byte offset (G4 swizzle, rule 21)
    const int srow = lane >> 3;
    const int soff = (srow << 7) + (((lane & 7) ^ srow) << 4);
    const int rx = ln15 & 7;
    const int c0 = (lhi ^ rx) << 3;
    const int c1 = ((4 + lhi) ^ rx) << 3;
    const int rbase = ln15 * 64;

    const int kbase = khalf << 9;

// shared staging: vgrp0 wave stages hi half, vgrp1 stages lo half (2 loads/wave)
#define STAGE(BUF, KT) { \
    const size_t tb_ = (size_t)(kbase + ((KT) << 4)) * DIM; \
    if (vgrp == 0) { \
        const unsigned char* g_ = (const unsigned char*)(ehib + tb_) + soff; \
        unsigned short* l_ = &stg[khalf][BUF][0]; \
        __builtin_amdgcn_global_load_lds((const g1_t*)g_,          (l3_t*)l_,          16, 0, 0); \
        __builtin_amdgcn_global_load_lds((const g1_t*)(g_ + 1024), (l3_t*)(l_ + 512),  16, 0, 0); \
    } else { \
        const unsigned char* g_ = (const unsigned char*)(elob + tb_) + soff; \
        unsigned short* l_ = &stg[khalf][BUF][1024]; \
        __builtin_amdgcn_global_load_lds((const g1_t*)g_,          (l3_t*)l_,          16, 0, 0); \
        __builtin_amdgcn_global_load_lds((const g1_t*)(g_ + 1024), (l3_t*)(l_ + 512),  16, 0, 0); \
    } \
}

    // packed keys: high 25 bits = positive-score float bits, low 7 = 127-local
    unsigned b1k[4] = {0, 0, 0, 0}, b2k[4] = {0, 0, 0, 0};

// BODY(CBUF = compute buffer, KT = tile, DOPRE, NBUF = stage buffer, VM = wait)
// order: counted wait -> barrier -> stage(kt+2) -> compute. Stage after barrier
// guarantees no wave still reads NBUF (it was computed at kt-1 by all waves).
#define BODY(CBUF, KT, DOPRE, NBUF, VM) { \
    asm volatile("s_waitcnt vmcnt(" VM ")" ::: "memory");   /* own half of KT landed */ \
    asm volatile("s_barrier" ::: "memory");                 /* other half landed too */ \
    if (DOPRE) STAGE(NBUF, (KT) + 2) \
    const unsigned short* lb = &stg[khalf][CBUF][0]; \
    const short8 ah0 = *(const short8*)(lb + rbase + c0); \
    const short8 ah1 = *(const short8*)(lb + rbase + c1); \
    const short8 al0 = *(const short8*)(lb + 1024 + rbase + c0); \
    const short8 al1 = *(const short8*)(lb + 1024 + rbase + c1); \
    const int k0_ = kbase + ((KT) << 4); \
    const f32x4 bias = *(const f32x4*)(&snl[k0_ + lhi * 4]); \
    const unsigned revb = 127u - (unsigned)((KT) << 2); \
    __builtin_amdgcn_s_setprio(1); \
    _Pragma("unroll") \
    for (int nt = 0; nt < 4; nt++) { \
        f32x4 acc = bias; \
        acc = __builtin_amdgcn_mfma_f32_16x16x32_bf16(ah0, xbh[nt][0], acc, 0, 0, 0); \
        acc = __builtin_amdgcn_mfma_f32_16x16x32_bf16(ah1, xbh[nt][1], acc, 0, 0, 0); \
        acc = __builtin_amdgcn_mfma_f32_16x16x32_bf16(ah0, xbl[nt][0], acc, 0, 0, 0); \
        acc = __builtin_amdgcn_mfma_f32_16x16x32_bf16(ah1, xbl[nt][1], acc, 0, 0, 0); \
        acc = __builtin_amdgcn_mfma_f32_16x16x32_bf16(al0, xbh[nt][0], acc, 0, 0, 0); \
        acc = __builtin_amdgcn_mfma_f32_16x16x32_bf16(al1, xbh[nt][1], acc, 0, 0, 0); \
        _Pragma("unroll") \
        for (int r = 0; r < 4; r++) { \
            const unsigned key = (__float_as_uint(acc[r]) & MSK7) | (revb - r); \
            b2k[nt] = umx(b2k[nt], umn(b1k[nt], key)); \
            b1k[nt] = umx(b1k[nt], key); \
        } \
    } \
    __builtin_amdgcn_s_setprio(0); \
}

    STAGE(0, 0)
    STAGE(1, 1)
    #pragma unroll 1
    for (int kt3 = 0; kt3 < 30; kt3 += 3) {
        BODY(0, kt3,     1, 2, "2")
        BODY(1, kt3 + 1, 1, 0, "2")
        BODY(2, kt3 + 2, 1, 1, "2")
    }
    BODY(0, 30, 0, 0, "2")
    BODY(1, 31, 0, 0, "0")
#undef STAGE
#undef BODY

    // ---- unpack, then merge top-2 across the 4 lane-groups ----
    #pragma unroll
    for (int nt = 0; nt < 4; nt++) {
        float B1 = __uint_as_float(b1k[nt] & MSK7);
        float B2 = __uint_as_float(b2k[nt] & MSK7);
        const int local = 127 - (int)(b1k[nt] & 127u);          // kt*4 + r
        int I = kbase + ((local >> 2) << 4) + lhi * 4 + (local & 3);
        #pragma unroll
        for (int off = 16; off <= 32; off <<= 1) {
            const float o1 = __shfl_xor(B1, off, 64);
            const float o2 = __shfl_xor(B2, off, 64);
            const int   oi = __shfl_xor(I,  off, 64);
            const float nb2 = fmaxf(fminf(B1, o1), fmaxf(B2, o2));
            if (o1 > B1 || (o1 == B1 && oi < I)) { B1 = o1; I = oi; }
            B2 = nb2;
        }
        if (khalf == 1 && lane < 16) {
            const int vloc = vgrp * 64 + nt * 16 + lane;
            red[vloc][0] = B1; red[vloc][1] = B2; red[vloc][2] = __int_as_float(I);
        }
        b1k[nt] = __float_as_uint(B1); b2k[nt] = __float_as_uint(B2);
        if (lane < 16 && khalf == 0) sidx[vgrp * 64 + nt * 16 + lane] = I; // temp park
    }
    __syncthreads();

    if (khalf == 0) {
        #pragma unroll
        for (int nt = 0; nt < 4; nt++) {
            if (lane < 16) {
                const int vloc = vgrp * 64 + nt * 16 + lane;
                const float ob1 = red[vloc][0];
                const float ob2 = red[vloc][1];
                const int   oi  = __float_as_int(red[vloc][2]);
                float B1 = __uint_as_float(b1k[nt]);
                float B2 = __uint_as_float(b2k[nt]);
                int I = sidx[vloc];
                if (ob1 > B1) { B2 = fmaxf(B1, ob2); B1 = ob1; I = oi; }  // kh0 idx < kh1 idx
                else          { B2 = fmaxf(B2, ob1); }
                sidx[vloc] = (B1 - B2 <= SMARGIN) ? -1 : I;
            }
        }
    }
    __syncthreads();

    // ---- epilogue: thread = (vector vloc, dim half dh); writes out + xT ----
    const int vloc = tid & 127;
    const int dh   = tid >> 7;           // 32-dim half
    const int t    = tblk + vloc;
    const int I    = sidx[vloc];
    const int v    = (b << 13) + t;

    float xf[32];
    #pragma unroll
    for (int j = 0; j < 32; j++) xf[j] = xb[((size_t)(dh * 32 + j) << 13) + t];

    if (use_xt) {                        // xT row for the code-reduce
        float4* xtp = (float4*)(xT + (size_t)v * 64 + dh * 32);
        #pragma unroll
        for (int q = 0; q < 8; q++) {
            float4 w; w.x = xf[q*4]; w.y = xf[q*4+1]; w.z = xf[q*4+2]; w.w = xf[q*4+3];
            xtp[q] = w;
        }
    }

    if (I < 0) {
        if (dh == 0) { const int p = atomicAdd(flagcnt, 1); flagids[p] = v; }
    } else {
        if (dh == 0) { idx32[v] = I; atomicAdd(&hcnt[I], 1); }
        const float4* eq4 = (const float4*)(emb + I * DIM + dh * 32);
        #pragma unroll
        for (int q = 0; q < 8; q++) {
            const float4 e4 = eq4[q];
            const int d = dh * 32 + q * 4;
            out[((size_t)b << 19) + ((size_t)(d + 0) << 13) + t] = xf[q*4+0] + (e4.x - xf[q*4+0]);
            out[((size_t)b << 19) + ((size_t)(d + 1) << 13) + t] = xf[q*4+1] + (e4.y - xf[q*4+1]);
            out[((size_t)b << 19) + ((size_t)(d + 2) << 13) + t] = xf[q*4+2] + (e4.z - xf[q*4+2]);
            out[((size_t)b << 19) + ((size_t)(d + 3) << 13) + t] = xf[q*4+3] + (e4.w - xf[q*4+3]);
        }
    }
    __syncthreads();
    #pragma unroll
    for (int q = 0; q < 4; q++) {
        const int c = hcnt[tid + q * 256];
        if (c) atomicAdd(&counts[tid + q * 256], c);
    }
}

// ---- rescan: block = 4 waves x SAME 4 vectors, k-split x4; exact fp64 ----
__global__ __launch_bounds__(256) void vq_rescan(const float* __restrict__ x,
                                                 const float* __restrict__ emb,
                                                 const double* __restrict__ e64,
                                                 const double* __restrict__ snh64,
                                                 float* __restrict__ out,
                                                 int* __restrict__ idx32,
                                                 int* __restrict__ counts,
                                                 const int* __restrict__ flagcnt,
                                                 const int* __restrict__ flagids) {
    __shared__ double rb[4][4];          // [kquarter][vx] wave best
    __shared__ int    ri[4][4];
    __shared__ int    rf[4];             // merged idx per vx
    const int tid   = threadIdx.x;
    const int wid   = tid >> 6;          // k-quarter (0..3)
    const int lane  = tid & 63;
    const int cslot = lane >> 2;         // 0..15 code slot
    const int dg    = lane & 3;          // 16-dim group
    const int count = *flagcnt;

    for (int base = blockIdx.x * 4; base < count; base += gridDim.x * 4) {
        bool act[4]; int vv[4];
        const float* xbp[4];
        double xd[4][16];
        #pragma unroll
        for (int vx = 0; vx < 4; vx++) {
            const int i = base + vx;
            act[vx] = i < count;
            const int v = flagids[act[vx] ? i : 0];
            vv[vx] = v;
            const int b = v >> 13, t = v & (T_ - 1);
            xbp[vx] = x + ((size_t)b << 19) + t;
            #pragma unroll
            for (int j = 0; j < 16; j++)
                xd[vx][j] = act[vx] ? (double)xbp[vx][(size_t)(dg * 16 + j) << 13] : 0.0;
        }

        double best[4] = {-1e300, -1e300, -1e300, -1e300};
        int    bi_[4]  = {0, 0, 0, 0};
        const int kq = wid << 8;         // this wave's 256 codes

        #pragma unroll 4
        for (int cc = 0; cc < 16; cc++) {
            const int k = kq + cc * 16 + cslot;           // in-lane k ascends with cc
            const double* ek = e64 + (size_t)k * DIM + dg * 16;
            const double snh = snh64[k];
            #pragma unroll
            for (int vx = 0; vx < 4; vx++) {
                double a0 = 0.0, a1 = 0.0, a2 = 0.0, a3 = 0.0;
                #pragma unroll
                for (int j = 0; j < 16; j += 4) {
                    a0 = __fma_rn(xd[vx][j + 0], ek[j + 0], a0);
                    a1 = __fma_rn(xd[vx][j + 1], ek[j + 1], a1);
                    a2 = __fma_rn(xd[vx][j + 2], ek[j + 2], a2);
                    a3 = __fma_rn(xd[vx][j + 3], ek[j + 3], a3);
                }
                double a = (a0 + a1) + (a2 + a3);
                a += __shfl_xor(a, 1, 64);
                a += __shfl_xor(a, 2, 64);                // full dot over 4 dim-groups
                const double m = a - snh;
                if (m > best[vx]) { best[vx] = m; bi_[vx] = k; }
            }
        }

        #pragma unroll
        for (int vx = 0; vx < 4; vx++) {
            double bb = best[vx]; int ii = bi_[vx];
            #pragma unroll
            for (int off = 4; off <= 32; off <<= 1) {     // merge across cslots
                const double ob = __shfl_xor(bb, off, 64);
                const int    oi = __shfl_xor(ii, off, 64);
                if (ob > bb || (ob == bb && oi < ii)) { bb = ob; ii = oi; }
            }
            if (lane == 0) { rb[wid][vx] = bb; ri[wid][vx] = ii; }
        }
        __syncthreads();
        if (tid < 4) {                    // thread vx: merge quarters ascending
            double bb = rb[0][tid]; int ii = ri[0][tid];
            #pragma unroll
            for (int w = 1; w < 4; w++) {
                if (rb[w][tid] > bb) { bb = rb[w][tid]; ii = ri[w][tid]; }  // strict >: lower k wins ties
            }
            rf[tid] = ii;
        }
        __syncthreads();

        {   // epilogue: wave wid handles vector wid; lane = dim
            const int vx = wid;
            if (act[vx]) {
                const int v = vv[vx];
                const int b = v >> 13, t = v & (T_ - 1);
                const int I = rf[vx];
                const float xf = xbp[vx][(size_t)lane << 13];
                out[((size_t)b << 19) + ((size_t)lane << 13) + t] =
                    xf + (emb[I * DIM + lane] - xf);
                if (lane == 0) { idx32[v] = I; atomicAdd(&counts[I], 1); }
            }
        }
        __syncthreads();                  // protect rb/ri/rf for next iteration
    }
}

// ---- scatter (scan fused, 1024 thr): scan counts, then counting-sort ----
__global__ __launch_bounds__(1024) void vq_scatter(const int* __restrict__ idx32,
                                                   const int* __restrict__ counts,
                                                   int* __restrict__ cnt2,
                                                   int* __restrict__ offsets,
                                                   int* __restrict__ order) {
    __shared__ int soff[K_CODES];
    __shared__ int wtot[16];
    const int tid  = threadIdx.x;
    const int lane = tid & 63;
    const int w    = tid >> 6;

    const int c = counts[tid];
    int s = c;
    #pragma unroll
    for (int off = 1; off < 64; off <<= 1) {
        const int o = __shfl_up(s, off, 64);
        if (lane >= off) s += o;
    }
    if (lane == 63) wtot[w] = s;
    __syncthreads();
    if (tid < 16) {
        int ws_ = wtot[tid];
        #pragma unroll
        for (int off = 1; off < 16; off <<= 1) {
            const int o = __shfl_up(ws_, off, 64);
            if (tid >= off) ws_ += o;
        }
        wtot[tid] = ws_;                 // inclusive scan of wave totals
    }
    __syncthreads();
    const int wbase = (w > 0) ? wtot[w - 1] : 0;
    soff[tid] = wbase + s - c;           // exclusive prefix
    __syncthreads();
    if (blockIdx.x == 0) offsets[tid] = soff[tid];   // publish for vq_reduce8

    const int v = blockIdx.x * 1024 + tid;
    const int k = idx32[v];
    const int p = soff[k] + atomicAdd(&cnt2[k], 1);
    order[p] = v;
}

// ---- reduce8: 8 slices per code; 4-deep gather; partials to scratch ----
__global__ __launch_bounds__(256) void vq_reduce8(const float* __restrict__ xT,
                                                  const int* __restrict__ order,
                                                  const int* __restrict__ offsets,
                                                  const int* __restrict__ counts,
                                                  float* __restrict__ partials) {
    __shared__ int lv[1024];
    __shared__ float ps[4][64];
    const int k   = blockIdx.x >> 3;
    const int sl  = blockIdx.x & 7;
    const int tid = threadIdx.x;
    const int i4  = tid >> 6;
    const int d   = tid & 63;
    const int cnt = counts[k];
    const int chunk = (cnt + 7) >> 3;
    const int lo = sl * chunk;
    const int hi = min(cnt, lo + chunk);
    const int off = offsets[k] + lo;
    const int n = hi - lo;

    float sum = 0.f;
    for (int base = 0; base < n; base += 1024) {
        const int m = min(1024, n - base);
        __syncthreads();
        for (int i = tid; i < m; i += 256) lv[i] = order[off + base + i];
        __syncthreads();
        float s0 = 0.f, s1 = 0.f, s2 = 0.f, s3 = 0.f;
        int i = i4;
        for (; i + 12 < m; i += 16) {                // 4-deep to keep loads in flight
            s0 += xT[(size_t)lv[i] * 64 + d];
            s1 += xT[(size_t)lv[i + 4] * 64 + d];
            s2 += xT[(size_t)lv[i + 8] * 64 + d];
            s3 += xT[(size_t)lv[i + 12] * 64 + d];
        }
        for (; i < m; i += 4) s0 += xT[(size_t)lv[i] * 64 + d];
        sum += (s0 + s1) + (s2 + s3);
    }
    __syncthreads();
    ps[i4][d] = sum;
    __syncthreads();
    if (i4 == 0)
        partials[(((size_t)sl << 10) + k) * 64 + d] = ps[0][d] + ps[1][d] + ps[2][d] + ps[3][d];
}

// ---- fin: sum 8 partials, divide by cluster_size ----
__global__ __launch_bounds__(64) void vq_fin(const float* __restrict__ partials,
                                             const int* __restrict__ counts,
                                             float* __restrict__ newemb) {
    const int k = blockIdx.x;
    const int d = threadIdx.x;
    float tot = 0.f;
    #pragma unroll
    for (int sl = 0; sl < 8; sl++) tot += partials[(((size_t)sl << 10) + k) * 64 + d];
    const float c = (float)counts[k];
    const float cluster = (c + EPSF) / (131072.0f + 1024.0f * EPSF) * 131072.0f;
    newemb[k * DIM + d] = tot / cluster;
}

// ---- reduce (fallback, ws too small for partials): block per code ----
__global__ __launch_bounds__(256) void vq_reduce(const float* __restrict__ x,
                                                 const float* __restrict__ xT,
                                                 const int* __restrict__ order,
                                                 const int* __restrict__ offsets,
                                                 const int* __restrict__ counts,
                                                 float* __restrict__ newemb,
                                                 int use_xt) {
    __shared__ int lv[1024];
    __shared__ float ps[4][64];
    const int k = blockIdx.x;
    const int tid = threadIdx.x;
    const int i4 = tid >> 6;
    const int d = tid & 63;
    const int off = offsets[k];
    const int cnt = counts[k];
    float sum = 0.f;
    for (int base = 0; base < cnt; base += 1024) {
        const int m = min(1024, cnt - base);
        __syncthreads();
        for (int i = tid; i < m; i += 256) lv[i] = order[off + base + i];
        __syncthreads();
        if (use_xt) {
            for (int i = i4; i < m; i += 4) sum += xT[(size_t)lv[i] * 64 + d];
        } else {
            for (int i = i4; i < m; i += 4) {
                const int v = lv[i];
                sum += x[((size_t)(v >> 13) << 19) + ((size_t)d << 13) + (v & (T_ - 1))];
            }
        }
    }
    __syncthreads();
    ps[i4][d] = sum;
    __syncthreads();
    if (i4 == 0) {
        const float tot = ps[0][d] + ps[1][d] + ps[2][d] + ps[3][d];
        const float c = (float)cnt;
        const float cluster = (c + EPSF) / (131072.0f + 1024.0f * EPSF) * 131072.0f;
        newemb[k * DIM + d] = tot / cluster;
    }
}

extern "C" void kernel_launch(void* const* d_in, const int* in_sizes, int n_in,
                              void* d_out, int out_size, void* d_ws, size_t ws_size,
                              hipStream_t stream) {
    const float* x   = (const float*)d_in[0];
    const float* emb = (const float*)d_in[1];

    char* ws = (char*)d_ws;
    double*         e64     = (double*)(ws);                  //  524288 B
    double*         snh64   = (double*)(ws + 524288);         //    8192 B
    float*          snb32   = (float*)(ws + 532480);          //    4096 B
    unsigned short* ehib    = (unsigned short*)(ws + 536576); //  131072 B
    unsigned short* elob    = (unsigned short*)(ws + 667648); //  131072 B
    int*            idx32   = (int*)(ws + 798720);            //  524288 B
    int*            order   = (int*)(ws + 1323008);           //  524288 B
    int*            counts  = (int*)(ws + 1847296);           //    4096 B
    int*            flagcnt = (int*)(ws + 1851392);           //      64 B
    int*            offsets = (int*)(ws + 1851456);           //    4096 B
    int*            cnt2    = (int*)(ws + 1855552);           //    4096 B
    int*            flagids = (int*)(ws + 1859648);           //  524288 B
    float*          xT      = (float*)(ws + 2383936);         // 33554432 B (optional)
    float*          part8   = (float*)(ws + 35938368);        //  2097152 B (optional)
    const int use_xt = (ws_size >= (size_t)2383936 + 33554432) ? 1 : 0;
    const int use_p8 = (use_xt && ws_size >= (size_t)35938368 + 2097152) ? 1 : 0;

    float* out    = (float*)d_out;
    float* newemb = out + (size_t)B_ * DIM * T_;

    vq_prep<<<K_CODES, 64, 0, stream>>>(emb, e64, snh64, snb32, ehib, elob,
                                        counts, cnt2, flagcnt);
    vq_screen<<<N_ / 128, 256, 0, stream>>>(x, ehib, elob, snb32, emb, out, xT, idx32,
                                            counts, flagcnt, flagids, use_xt);
    vq_rescan<<<2048, 256, 0, stream>>>(x, emb, e64, snh64, out, idx32, counts,
                                        flagcnt, flagids);
    vq_scatter<<<N_ / 1024, 1024, 0, stream>>>(idx32, counts, cnt2, offsets, order);
    if (use_p8) {
        vq_reduce8<<<K_CODES * 8, 256, 0, stream>>>(xT, order, offsets, counts, part8);
        vq_fin<<<K_CODES, 64, 0, stream>>>(part8, counts, newemb);
    } else {
        vq_reduce<<<K_CODES, 256, 0, stream>>>(x, xT, order, offsets, counts, newemb, use_xt);
    }
}

// Round 21
// 162.929 us; speedup vs baseline: 1.6157x; 1.0046x over previous
//
#include <hip/hip_runtime.h>

#define K_CODES 1024
#define DIM 64
#define B_ 16
#define T_ 8192
#define N_ (B_*T_)          // 131072 vectors
#define EPSF 1e-5f
#define SMARGIN 5e-4f       // exact-float margin; > 2x the 7-bit key quantum 2.44e-4
#define MSK7 0xFFFFFF80u

typedef __attribute__((ext_vector_type(8))) short short8;   // 8 bf16 = 4 VGPR
typedef __attribute__((ext_vector_type(4))) float f32x4;

typedef __attribute__((address_space(1))) unsigned char g1_t;   // global
typedef __attribute__((address_space(3))) unsigned char l3_t;   // LDS

__device__ __forceinline__ unsigned bf16_rne(float f) {
    unsigned u = __float_as_uint(f);
    return (u + 0x7fffu + ((u >> 16) & 1u)) >> 16;
}
__device__ __forceinline__ unsigned umx(unsigned a, unsigned b) { return a > b ? a : b; }
__device__ __forceinline__ unsigned umn(unsigned a, unsigned b) { return a < b ? a : b; }

// ---- prep: e -> bf16 hi/lo tables, fp64 table, norms; zero accumulators ----
__global__ __launch_bounds__(64) void vq_prep(const float* __restrict__ emb,
                                              double* __restrict__ e64,
                                              double* __restrict__ snh64,
                                              float* __restrict__ snb32,
                                              unsigned short* __restrict__ ehib,
                                              unsigned short* __restrict__ elob,
                                              int* __restrict__ counts,
                                              int* __restrict__ cnt2,
                                              int* __restrict__ flagcnt) {
    const int k = blockIdx.x;
    const int d = threadIdx.x;
    if (d == 0) counts[k] = 0;
    if (d == 1) cnt2[k] = 0;
    if (k == 0 && d == 2) *flagcnt = 0;

    const float ef = emb[k * DIM + d];
    const unsigned rh = bf16_rne(ef);
    const float hif = __uint_as_float(rh << 16);
    const float lof = ef - hif;                   // exact (Sterbenz)
    const unsigned rl = bf16_rne(lof);
    ehib[k * DIM + d] = (unsigned short)rh;
    elob[k * DIM + d] = (unsigned short)rl;

    const double ed = (double)ef;
    e64[k * DIM + d] = ed;
    double s = ed * ed;
    #pragma unroll
    for (int off = 32; off; off >>= 1) s += __shfl_down(s, off, 64);
    if (d == 0) {
        snh64[k] = 0.5 * s;
        snb32[k] = (float)(16.0 - 0.5 * s);   // +16 bias: scores in (8,24), positive
    }
}

// ---- screen: split-bf16 MFMA, packed-key top-2, T3/T4 pipelined staging ----
// block = 4 waves = 2 vgrp(64 vec) x 2 khalf(512 codes); 128 vec/block; grid 1024.
// Triple-buffered shared e-staging, counted vmcnt(2), raw s_barrier (no drain).
// launch_bounds(256,5): cap VGPR at 102 -> 5 waves/SIMD (was 108 -> 4).
__global__ __launch_bounds__(256, 5) void vq_screen(const float* __restrict__ x,
                                                 const unsigned short* __restrict__ ehib,
                                                 const unsigned short* __restrict__ elob,
                                                 const float* __restrict__ snb32,
                                                 const float* __restrict__ emb,
                                                 float* __restrict__ out,
                                                 float* __restrict__ xT,
                                                 int* __restrict__ idx32,
                                                 int* __restrict__ counts,
                                                 int* __restrict__ flagcnt,
                                                 int* __restrict__ flagids,
                                                 int use_xt) {
    __shared__ unsigned short stg[2][3][2048]; // [khalf][buf][hi 1024hw | lo 1024hw]
    __shared__ float snl[K_CODES];             // biased norms in LDS (loop has no VMEM)
    __shared__ float red[128][4];              // khalf=1: b1, b2, idx-bits
    __shared__ int sidx[128];                  // merged: code index, or -1 = flagged
    __shared__ int hcnt[K_CODES];              // per-block histogram

    const int tid   = threadIdx.x;
    const int wid   = tid >> 6;
    const int lane  = tid & 63;
    const int vgrp  = wid & 1;
    const int khalf = wid >> 1;
    const int ln15  = lane & 15;
    const int lhi   = lane >> 4;               // 0..3

    #pragma unroll
    for (int q = 0; q < 4; q++) hcnt[tid + q * 256] = 0;

    const int blk  = blockIdx.x;               // 1024 blocks x 128 vectors
    const int b    = blk >> 6;
    const int tblk = (blk & 63) << 7;
    const int t0   = tblk + vgrp * 64;
    const float* xb = x + ((size_t)b << 19);

    // ---- stage biased norms to LDS (vgrp0 waves only; oldest in vm queue) ----
    if (vgrp == 0) {
        const unsigned char* gs = (const unsigned char*)(snb32 + (khalf << 9));
        unsigned char* ls = (unsigned char*)&snl[khalf << 9];
        __builtin_amdgcn_global_load_lds((const g1_t*)(gs + lane * 16),        (l3_t*)ls,          16, 0, 0);
        __builtin_amdgcn_global_load_lds((const g1_t*)(gs + 1024 + lane * 16), (l3_t*)(ls + 1024), 16, 0, 0);
    }

    // ---- x B-fragments (hi/lo), register-resident ----
    short8 xbh[4][2], xbl[4][2];
    #pragma unroll
    for (int nt = 0; nt < 4; nt++) {
        const int t = t0 + nt * 16 + ln15;
        #pragma unroll
        for (int s = 0; s < 2; s++) {
            #pragma unroll
            for (int j = 0; j < 8; j++) {
                const int d = s * 32 + lhi * 8 + j;
                const float xf = xb[((size_t)d << 13) + t];
                const unsigned rh = bf16_rne(xf);
                const float hif = __uint_as_float(rh << 16);
                const unsigned rl = bf16_rne(xf - hif);
                xbh[nt][s][j] = (short)rh;
                xbl[nt][s][j] = (short)rl;
            }
        }
    }

    // staging: pre-swizzled source byte offset (G4 swizzle, rule 21)
    const int srow = lane >> 3;
    const int soff = (srow << 7) + (((lane & 7) ^ srow) << 4);
    const int rx = ln15 & 7;
    const int c0 = (lhi ^ rx) << 3;
    const int c1 = ((4 + lhi) ^ rx) << 3;
    const int rbase = ln15 * 64;

    const int kbase = khalf << 9;

// shared staging: vgrp0 wave stages hi half, vgrp1 stages lo half (2 loads/wave)
#define STAGE(BUF, KT) { \
    const size_t tb_ = (size_t)(kbase + ((KT) << 4)) * DIM; \
    if (vgrp == 0) { \
        const unsigned char* g_ = (const unsigned char*)(ehib + tb_) + soff; \
        unsigned short* l_ = &stg[khalf][BUF][0]; \
        __builtin_amdgcn_global_load_lds((const g1_t*)g_,          (l3_t*)l_,          16, 0, 0); \
        __builtin_amdgcn_global_load_lds((const g1_t*)(g_ + 1024), (l3_t*)(l_ + 512),  16, 0, 0); \
    } else { \
        const unsigned char* g_ = (const unsigned char*)(elob + tb_) + soff; \
        unsigned short* l_ = &stg[khalf][BUF][1024]; \
        __builtin_amdgcn_global_load_lds((const g1_t*)g_,          (l3_t*)l_,          16, 0, 0); \
        __builtin_amdgcn_global_load_lds((const g1_t*)(g_ + 1024), (l3_t*)(l_ + 512),  16, 0, 0); \
    } \
}

    // packed keys: high 25 bits = positive-score float bits, low 7 = 127-local
    unsigned b1k[4] = {0, 0, 0, 0}, b2k[4] = {0, 0, 0, 0};

// BODY(CBUF = compute buffer, KT = tile, DOPRE, NBUF = stage buffer, VM = wait)
// order: counted wait -> barrier -> stage(kt+2) -> compute. Stage after barrier
// guarantees no wave still reads NBUF (it was computed at kt-1 by all waves).
#define BODY(CBUF, KT, DOPRE, NBUF, VM) { \
    asm volatile("s_waitcnt vmcnt(" VM ")" ::: "memory");   /* own half of KT landed */ \
    asm volatile("s_barrier" ::: "memory");                 /* other half landed too */ \
    if (DOPRE) STAGE(NBUF, (KT) + 2) \
    const unsigned short* lb = &stg[khalf][CBUF][0]; \
    const short8 ah0 = *(const short8*)(lb + rbase + c0); \
    const short8 ah1 = *(const short8*)(lb + rbase + c1); \
    const short8 al0 = *(const short8*)(lb + 1024 + rbase + c0); \
    const short8 al1 = *(const short8*)(lb + 1024 + rbase + c1); \
    const int k0_ = kbase + ((KT) << 4); \
    const f32x4 bias = *(const f32x4*)(&snl[k0_ + lhi * 4]); \
    const unsigned revb = 127u - (unsigned)((KT) << 2); \
    __builtin_amdgcn_s_setprio(1); \
    _Pragma("unroll") \
    for (int nt = 0; nt < 4; nt++) { \
        f32x4 acc = bias; \
        acc = __builtin_amdgcn_mfma_f32_16x16x32_bf16(ah0, xbh[nt][0], acc, 0, 0, 0); \
        acc = __builtin_amdgcn_mfma_f32_16x16x32_bf16(ah1, xbh[nt][1], acc, 0, 0, 0); \
        acc = __builtin_amdgcn_mfma_f32_16x16x32_bf16(ah0, xbl[nt][0], acc, 0, 0, 0); \
        acc = __builtin_amdgcn_mfma_f32_16x16x32_bf16(ah1, xbl[nt][1], acc, 0, 0, 0); \
        acc = __builtin_amdgcn_mfma_f32_16x16x32_bf16(al0, xbh[nt][0], acc, 0, 0, 0); \
        acc = __builtin_amdgcn_mfma_f32_16x16x32_bf16(al1, xbh[nt][1], acc, 0, 0, 0); \
        _Pragma("unroll") \
        for (int r = 0; r < 4; r++) { \
            const unsigned key = (__float_as_uint(acc[r]) & MSK7) | (revb - r); \
            b2k[nt] = umx(b2k[nt], umn(b1k[nt], key)); \
            b1k[nt] = umx(b1k[nt], key); \
        } \
    } \
    __builtin_amdgcn_s_setprio(0); \
}

    STAGE(0, 0)
    STAGE(1, 1)
    #pragma unroll 1
    for (int kt3 = 0; kt3 < 30; kt3 += 3) {
        BODY(0, kt3,     1, 2, "2")
        BODY(1, kt3 + 1, 1, 0, "2")
        BODY(2, kt3 + 2, 1, 1, "2")
    }
    BODY(0, 30, 0, 0, "2")
    BODY(1, 31, 0, 0, "0")
#undef STAGE
#undef BODY

    // ---- unpack, then merge top-2 across the 4 lane-groups ----
    #pragma unroll
    for (int nt = 0; nt < 4; nt++) {
        float B1 = __uint_as_float(b1k[nt] & MSK7);
        float B2 = __uint_as_float(b2k[nt] & MSK7);
        const int local = 127 - (int)(b1k[nt] & 127u);          // kt*4 + r
        int I = kbase + ((local >> 2) << 4) + lhi * 4 + (local & 3);
        #pragma unroll
        for (int off = 16; off <= 32; off <<= 1) {
            const float o1 = __shfl_xor(B1, off, 64);
            const float o2 = __shfl_xor(B2, off, 64);
            const int   oi = __shfl_xor(I,  off, 64);
            const float nb2 = fmaxf(fminf(B1, o1), fmaxf(B2, o2));
            if (o1 > B1 || (o1 == B1 && oi < I)) { B1 = o1; I = oi; }
            B2 = nb2;
        }
        if (khalf == 1 && lane < 16) {
            const int vloc = vgrp * 64 + nt * 16 + lane;
            red[vloc][0] = B1; red[vloc][1] = B2; red[vloc][2] = __int_as_float(I);
        }
        b1k[nt] = __float_as_uint(B1); b2k[nt] = __float_as_uint(B2);
        if (lane < 16 && khalf == 0) sidx[vgrp * 64 + nt * 16 + lane] = I; // temp park
    }
    __syncthreads();

    if (khalf == 0) {
        #pragma unroll
        for (int nt = 0; nt < 4; nt++) {
            if (lane < 16) {
                const int vloc = vgrp * 64 + nt * 16 + lane;
                const float ob1 = red[vloc][0];
                const float ob2 = red[vloc][1];
                const int   oi  = __float_as_int(red[vloc][2]);
                float B1 = __uint_as_float(b1k[nt]);
                float B2 = __uint_as_float(b2k[nt]);
                int I = sidx[vloc];
                if (ob1 > B1) { B2 = fmaxf(B1, ob2); B1 = ob1; I = oi; }  // kh0 idx < kh1 idx
                else          { B2 = fmaxf(B2, ob1); }
                sidx[vloc] = (B1 - B2 <= SMARGIN) ? -1 : I;
            }
        }
    }
    __syncthreads();

    // ---- epilogue: thread = (vector vloc, dim half dh), chunked (low VGPR) ----
    const int vloc = tid & 127;
    const int dh   = tid >> 7;           // 32-dim half
    const int t    = tblk + vloc;
    const int I    = sidx[vloc];
    const int v    = (b << 13) + t;

    if (I < 0) {
        if (dh == 0) { const int p = atomicAdd(flagcnt, 1); flagids[p] = v; }
    } else if (dh == 0) {
        idx32[v] = I; atomicAdd(&hcnt[I], 1);
    }

    const float* xp = xb + t;
    float4* xtp = (float4*)(xT + (size_t)v * 64 + dh * 32);
    const float4* eq4 = (const float4*)(emb + ((I >= 0 ? I : 0) * DIM) + dh * 32);
    #pragma unroll 2
    for (int q = 0; q < 8; q++) {
        const int d = dh * 32 + q * 4;
        float4 w;
        w.x = xp[(size_t)(d + 0) << 13];
        w.y = xp[(size_t)(d + 1) << 13];
        w.z = xp[(size_t)(d + 2) << 13];
        w.w = xp[(size_t)(d + 3) << 13];
        if (use_xt) xtp[q] = w;
        if (I >= 0) {
            const float4 e4 = eq4[q];
            out[((size_t)b << 19) + ((size_t)(d + 0) << 13) + t] = w.x + (e4.x - w.x);
            out[((size_t)b << 19) + ((size_t)(d + 1) << 13) + t] = w.y + (e4.y - w.y);
            out[((size_t)b << 19) + ((size_t)(d + 2) << 13) + t] = w.z + (e4.z - w.z);
            out[((size_t)b << 19) + ((size_t)(d + 3) << 13) + t] = w.w + (e4.w - w.w);
        }
    }
    __syncthreads();
    #pragma unroll
    for (int q = 0; q < 4; q++) {
        const int c = hcnt[tid + q * 256];
        if (c) atomicAdd(&counts[tid + q * 256], c);
    }
}

// ---- rescan: block = 4 waves x SAME 4 vectors, k-split x4; exact fp64 ----
__global__ __launch_bounds__(256) void vq_rescan(const float* __restrict__ x,
                                                 const float* __restrict__ emb,
                                                 const double* __restrict__ e64,
                                                 const double* __restrict__ snh64,
                                                 float* __restrict__ out,
                                                 int* __restrict__ idx32,
                                                 int* __restrict__ counts,
                                                 const int* __restrict__ flagcnt,
                                                 const int* __restrict__ flagids) {
    __shared__ double rb[4][4];          // [kquarter][vx] wave best
    __shared__ int    ri[4][4];
    __shared__ int    rf[4];             // merged idx per vx
    const int tid   = threadIdx.x;
    const int wid   = tid >> 6;          // k-quarter (0..3)
    const int lane  = tid & 63;
    const int cslot = lane >> 2;         // 0..15 code slot
    const int dg    = lane & 3;          // 16-dim group
    const int count = *flagcnt;

    for (int base = blockIdx.x * 4; base < count; base += gridDim.x * 4) {
        bool act[4]; int vv[4];
        const float* xbp[4];
        double xd[4][16];
        #pragma unroll
        for (int vx = 0; vx < 4; vx++) {
            const int i = base + vx;
            act[vx] = i < count;
            const int v = flagids[act[vx] ? i : 0];
            vv[vx] = v;
            const int b = v >> 13, t = v & (T_ - 1);
            xbp[vx] = x + ((size_t)b << 19) + t;
            #pragma unroll
            for (int j = 0; j < 16; j++)
                xd[vx][j] = act[vx] ? (double)xbp[vx][(size_t)(dg * 16 + j) << 13] : 0.0;
        }

        double best[4] = {-1e300, -1e300, -1e300, -1e300};
        int    bi_[4]  = {0, 0, 0, 0};
        const int kq = wid << 8;         // this wave's 256 codes

        #pragma unroll 4
        for (int cc = 0; cc < 16; cc++) {
            const int k = kq + cc * 16 + cslot;           // in-lane k ascends with cc
            const double* ek = e64 + (size_t)k * DIM + dg * 16;
            const double snh = snh64[k];
            #pragma unroll
            for (int vx = 0; vx < 4; vx++) {
                double a0 = 0.0, a1 = 0.0, a2 = 0.0, a3 = 0.0;
                #pragma unroll
                for (int j = 0; j < 16; j += 4) {
                    a0 = __fma_rn(xd[vx][j + 0], ek[j + 0], a0);
                    a1 = __fma_rn(xd[vx][j + 1], ek[j + 1], a1);
                    a2 = __fma_rn(xd[vx][j + 2], ek[j + 2], a2);
                    a3 = __fma_rn(xd[vx][j + 3], ek[j + 3], a3);
                }
                double a = (a0 + a1) + (a2 + a3);
                a += __shfl_xor(a, 1, 64);
                a += __shfl_xor(a, 2, 64);                // full dot over 4 dim-groups
                const double m = a - snh;
                if (m > best[vx]) { best[vx] = m; bi_[vx] = k; }
            }
        }

        #pragma unroll
        for (int vx = 0; vx < 4; vx++) {
            double bb = best[vx]; int ii = bi_[vx];
            #pragma unroll
            for (int off = 4; off <= 32; off <<= 1) {     // merge across cslots
                const double ob = __shfl_xor(bb, off, 64);
                const int    oi = __shfl_xor(ii, off, 64);
                if (ob > bb || (ob == bb && oi < ii)) { bb = ob; ii = oi; }
            }
            if (lane == 0) { rb[wid][vx] = bb; ri[wid][vx] = ii; }
        }
        __syncthreads();
        if (tid < 4) {                    // thread vx: merge quarters ascending
            double bb = rb[0][tid]; int ii = ri[0][tid];
            #pragma unroll
            for (int w = 1; w < 4; w++) {
                if (rb[w][tid] > bb) { bb = rb[w][tid]; ii = ri[w][tid]; }  // strict >: lower k wins ties
            }
            rf[tid] = ii;
        }
        __syncthreads();

        {   // epilogue: wave wid handles vector wid; lane = dim
            const int vx = wid;
            if (act[vx]) {
                const int v = vv[vx];
                const int b = v >> 13, t = v & (T_ - 1);
                const int I = rf[vx];
                const float xf = xbp[vx][(size_t)lane << 13];
                out[((size_t)b << 19) + ((size_t)lane << 13) + t] =
                    xf + (emb[I * DIM + lane] - xf);
                if (lane == 0) { idx32[v] = I; atomicAdd(&counts[I], 1); }
            }
        }
        __syncthreads();                  // protect rb/ri/rf for next iteration
    }
}

// ---- scatter (scan fused, 1024 thr): scan counts, then counting-sort ----
__global__ __launch_bounds__(1024) void vq_scatter(const int* __restrict__ idx32,
                                                   const int* __restrict__ counts,
                                                   int* __restrict__ cnt2,
                                                   int* __restrict__ offsets,
                                                   int* __restrict__ order) {
    __shared__ int soff[K_CODES];
    __shared__ int wtot[16];
    const int tid  = threadIdx.x;
    const int lane = tid & 63;
    const int w    = tid >> 6;

    const int c = counts[tid];
    int s = c;
    #pragma unroll
    for (int off = 1; off < 64; off <<= 1) {
        const int o = __shfl_up(s, off, 64);
        if (lane >= off) s += o;
    }
    if (lane == 63) wtot[w] = s;
    __syncthreads();
    if (tid < 16) {
        int ws_ = wtot[tid];
        #pragma unroll
        for (int off = 1; off < 16; off <<= 1) {
            const int o = __shfl_up(ws_, off, 64);
            if (tid >= off) ws_ += o;
        }
        wtot[tid] = ws_;                 // inclusive scan of wave totals
    }
    __syncthreads();
    const int wbase = (w > 0) ? wtot[w - 1] : 0;
    soff[tid] = wbase + s - c;           // exclusive prefix
    __syncthreads();
    if (blockIdx.x == 0) offsets[tid] = soff[tid];   // publish for vq_reduce8

    const int v = blockIdx.x * 1024 + tid;
    const int k = idx32[v];
    const int p = soff[k] + atomicAdd(&cnt2[k], 1);
    order[p] = v;
}

// ---- reduce8: 8 slices per code; 4-deep gather; partials to scratch ----
__global__ __launch_bounds__(256) void vq_reduce8(const float* __restrict__ xT,
                                                  const int* __restrict__ order,
                                                  const int* __restrict__ offsets,
                                                  const int* __restrict__ counts,
                                                  float* __restrict__ partials) {
    __shared__ int lv[1024];
    __shared__ float ps[4][64];
    const int k   = blockIdx.x >> 3;
    const int sl  = blockIdx.x & 7;
    const int tid = threadIdx.x;
    const int i4  = tid >> 6;
    const int d   = tid & 63;
    const int cnt = counts[k];
    const int chunk = (cnt + 7) >> 3;
    const int lo = sl * chunk;
    const int hi = min(cnt, lo + chunk);
    const int off = offsets[k] + lo;
    const int n = hi - lo;

    float sum = 0.f;
    for (int base = 0; base < n; base += 1024) {
        const int m = min(1024, n - base);
        __syncthreads();
        for (int i = tid; i < m; i += 256) lv[i] = order[off + base + i];
        __syncthreads();
        float s0 = 0.f, s1 = 0.f, s2 = 0.f, s3 = 0.f;
        int i = i4;
        for (; i + 12 < m; i += 16) {                // 4-deep to keep loads in flight
            s0 += xT[(size_t)lv[i] * 64 + d];
            s1 += xT[(size_t)lv[i + 4] * 64 + d];
            s2 += xT[(size_t)lv[i + 8] * 64 + d];
            s3 += xT[(size_t)lv[i + 12] * 64 + d];
        }
        for (; i < m; i += 4) s0 += xT[(size_t)lv[i] * 64 + d];
        sum += (s0 + s1) + (s2 + s3);
    }
    __syncthreads();
    ps[i4][d] = sum;
    __syncthreads();
    if (i4 == 0)
        partials[(((size_t)sl << 10) + k) * 64 + d] = ps[0][d] + ps[1][d] + ps[2][d] + ps[3][d];
}

// ---- fin: sum 8 partials, divide by cluster_size ----
__global__ __launch_bounds__(64) void vq_fin(const float* __restrict__ partials,
                                             const int* __restrict__ counts,
                                             float* __restrict__ newemb) {
    const int k = blockIdx.x;
    const int d = threadIdx.x;
    float tot = 0.f;
    #pragma unroll
    for (int sl = 0; sl < 8; sl++) tot += partials[(((size_t)sl << 10) + k) * 64 + d];
    const float c = (float)counts[k];
    const float cluster = (c + EPSF) / (131072.0f + 1024.0f * EPSF) * 131072.0f;
    newemb[k * DIM + d] = tot / cluster;
}

// ---- reduce (fallback, ws too small for partials): block per code ----
__global__ __launch_bounds__(256) void vq_reduce(const float* __restrict__ x,
                                                 const float* __restrict__ xT,
                                                 const int* __restrict__ order,
                                                 const int* __restrict__ offsets,
                                                 const int* __restrict__ counts,
                                                 float* __restrict__ newemb,
                                                 int use_xt) {
    __shared__ int lv[1024];
    __shared__ float ps[4][64];
    const int k = blockIdx.x;
    const int tid = threadIdx.x;
    const int i4 = tid >> 6;
    const int d = tid & 63;
    const int off = offsets[k];
    const int cnt = counts[k];
    float sum = 0.f;
    for (int base = 0; base < cnt; base += 1024) {
        const int m = min(1024, cnt - base);
        __syncthreads();
        for (int i = tid; i < m; i += 256) lv[i] = order[off + base + i];
        __syncthreads();
        if (use_xt) {
            for (int i = i4; i < m; i += 4) sum += xT[(size_t)lv[i] * 64 + d];
        } else {
            for (int i = i4; i < m; i += 4) {
                const int v = lv[i];
                sum += x[((size_t)(v >> 13) << 19) + ((size_t)d << 13) + (v & (T_ - 1))];
            }
        }
    }
    __syncthreads();
    ps[i4][d] = sum;
    __syncthreads();
    if (i4 == 0) {
        const float tot = ps[0][d] + ps[1][d] + ps[2][d] + ps[3][d];
        const float c = (float)cnt;
        const float cluster = (c + EPSF) / (131072.0f + 1024.0f * EPSF) * 131072.0f;
        newemb[k * DIM + d] = tot / cluster;
    }
}

extern "C" void kernel_launch(void* const* d_in, const int* in_sizes, int n_in,
                              void* d_out, int out_size, void* d_ws, size_t ws_size,
                              hipStream_t stream) {
    const float* x   = (const float*)d_in[0];
    const float* emb = (const float*)d_in[1];

    char* ws = (char*)d_ws;
    double*         e64     = (double*)(ws);                  //  524288 B
    double*         snh64   = (double*)(ws + 524288);         //    8192 B
    float*          snb32   = (float*)(ws + 532480);          //    4096 B
    unsigned short* ehib    = (unsigned short*)(ws + 536576); //  131072 B
    unsigned short* elob    = (unsigned short*)(ws + 667648); //  131072 B
    int*            idx32   = (int*)(ws + 798720);            //  524288 B
    int*            order   = (int*)(ws + 1323008);           //  524288 B
    int*            counts  = (int*)(ws + 1847296);           //    4096 B
    int*            flagcnt = (int*)(ws + 1851392);           //      64 B
    int*            offsets = (int*)(ws + 1851456);           //    4096 B
    int*            cnt2    = (int*)(ws + 1855552);           //    4096 B
    int*            flagids = (int*)(ws + 1859648);           //  524288 B
    float*          xT      = (float*)(ws + 2383936);         // 33554432 B (optional)
    float*          part8   = (float*)(ws + 35938368);        //  2097152 B (optional)
    const int use_xt = (ws_size >= (size_t)2383936 + 33554432) ? 1 : 0;
    const int use_p8 = (use_xt && ws_size >= (size_t)35938368 + 2097152) ? 1 : 0;

    float* out    = (float*)d_out;
    float* newemb = out + (size_t)B_ * DIM * T_;

    vq_prep<<<K_CODES, 64, 0, stream>>>(emb, e64, snh64, snb32, ehib, elob,
                                        counts, cnt2, flagcnt);
    vq_screen<<<N_ / 128, 256, 0, stream>>>(x, ehib, elob, snb32, emb, out, xT, idx32,
                                            counts, flagcnt, flagids, use_xt);
    vq_rescan<<<2048, 256, 0, stream>>>(x, emb, e64, snh64, out, idx32, counts,
                                        flagcnt, flagids);
    vq_scatter<<<N_ / 1024, 1024, 0, stream>>>(idx32, counts, cnt2, offsets, order);
    if (use_p8) {
        vq_reduce8<<<K_CODES * 8, 256, 0, stream>>>(xT, order, offsets, counts, part8);
        vq_fin<<<K_CODES, 64, 0, stream>>>(part8, counts, newemb);
    } else {
        vq_reduce<<<K_CODES, 256, 0, stream>>>(x, xT, order, offsets, counts, newemb, use_xt);
    }
}

// Round 22
// 162.791 us; speedup vs baseline: 1.6170x; 1.0008x over previous
//
#include <hip/hip_runtime.h>

#define K_CODES 1024
#define DIM 64
#define B_ 16
#define T_ 8192
#define N_ (B_*T_)          // 131072 vectors
#define EPSF 1e-5f
#define SMARGIN 5e-4f       // exact-float margin; > 2x the 7-bit key quantum 2.44e-4
#define MSK7 0xFFFFFF80u

typedef __attribute__((ext_vector_type(8))) short short8;   // 8 bf16 = 4 VGPR
typedef __attribute__((ext_vector_type(4))) float f32x4;

typedef __attribute__((address_space(1))) unsigned char g1_t;   // global
typedef __attribute__((address_space(3))) unsigned char l3_t;   // LDS

__device__ __forceinline__ unsigned bf16_rne(float f) {
    unsigned u = __float_as_uint(f);
    return (u + 0x7fffu + ((u >> 16) & 1u)) >> 16;
}
__device__ __forceinline__ unsigned umx(unsigned a, unsigned b) { return a > b ? a : b; }
__device__ __forceinline__ unsigned umn(unsigned a, unsigned b) { return a < b ? a : b; }

// ---- prep: e -> bf16 hi/lo tables, fp64 table, norms; zero accumulators ----
__global__ __launch_bounds__(64) void vq_prep(const float* __restrict__ emb,
                                              double* __restrict__ e64,
                                              double* __restrict__ snh64,
                                              float* __restrict__ snb32,
                                              unsigned short* __restrict__ ehib,
                                              unsigned short* __restrict__ elob,
                                              int* __restrict__ counts,
                                              int* __restrict__ cnt2,
                                              int* __restrict__ flagcnt) {
    const int k = blockIdx.x;
    const int d = threadIdx.x;
    if (d == 0) counts[k] = 0;
    if (d == 1) cnt2[k] = 0;
    if (k == 0 && d == 2) *flagcnt = 0;

    const float ef = emb[k * DIM + d];
    const unsigned rh = bf16_rne(ef);
    const float hif = __uint_as_float(rh << 16);
    const float lof = ef - hif;                   // exact (Sterbenz)
    const unsigned rl = bf16_rne(lof);
    ehib[k * DIM + d] = (unsigned short)rh;
    elob[k * DIM + d] = (unsigned short)rl;

    const double ed = (double)ef;
    e64[k * DIM + d] = ed;
    double s = ed * ed;
    #pragma unroll
    for (int off = 32; off; off >>= 1) s += __shfl_down(s, off, 64);
    if (d == 0) {
        snh64[k] = 0.5 * s;
        snb32[k] = (float)(16.0 - 0.5 * s);   // +16 bias: scores in (8,24), positive
    }
}

// ---- screen: split-bf16 MFMA, packed-key top-2 (tree), T3/T4 pipelining ----
// block = 4 waves = 2 vgrp(64 vec) x 2 khalf(512 codes); 128 vec/block; grid 1024.
__global__ __launch_bounds__(256) void vq_screen(const float* __restrict__ x,
                                                 const unsigned short* __restrict__ ehib,
                                                 const unsigned short* __restrict__ elob,
                                                 const float* __restrict__ snb32,
                                                 const float* __restrict__ emb,
                                                 float* __restrict__ out,
                                                 float* __restrict__ xT,
                                                 int* __restrict__ idx32,
                                                 int* __restrict__ counts,
                                                 int* __restrict__ flagcnt,
                                                 int* __restrict__ flagids,
                                                 int use_xt) {
    __shared__ unsigned short stg[2][3][2048]; // [khalf][buf][hi 1024hw | lo 1024hw]
    __shared__ float snl[K_CODES];             // biased norms in LDS (loop has no VMEM)
    __shared__ float red[128][4];              // khalf=1: b1, b2, idx-bits
    __shared__ int sidx[128];                  // merged: code index, or -1 = flagged
    __shared__ int hcnt[K_CODES];              // per-block histogram

    const int tid   = threadIdx.x;
    const int wid   = tid >> 6;
    const int lane  = tid & 63;
    const int vgrp  = wid & 1;
    const int khalf = wid >> 1;
    const int ln15  = lane & 15;
    const int lhi   = lane >> 4;               // 0..3

    #pragma unroll
    for (int q = 0; q < 4; q++) hcnt[tid + q * 256] = 0;

    const int blk  = blockIdx.x;               // 1024 blocks x 128 vectors
    const int b    = blk >> 6;
    const int tblk = (blk & 63) << 7;
    const int t0   = tblk + vgrp * 64;
    const float* xb = x + ((size_t)b << 19);

    // ---- stage biased norms to LDS (vgrp0 waves only; oldest in vm queue) ----
    if (vgrp == 0) {
        const unsigned char* gs = (const unsigned char*)(snb32 + (khalf << 9));
        unsigned char* ls = (unsigned char*)&snl[khalf << 9];
        __builtin_amdgcn_global_load_lds((const g1_t*)(gs + lane * 16),        (l3_t*)ls,          16, 0, 0);
        __builtin_amdgcn_global_load_lds((const g1_t*)(gs + 1024 + lane * 16), (l3_t*)(ls + 1024), 16, 0, 0);
    }

    // ---- x B-fragments (hi/lo), register-resident ----
    short8 xbh[4][2], xbl[4][2];
    #pragma unroll
    for (int nt = 0; nt < 4; nt++) {
        const int t = t0 + nt * 16 + ln15;
        #pragma unroll
        for (int s = 0; s < 2; s++) {
            #pragma unroll
            for (int j = 0; j < 8; j++) {
                const int d = s * 32 + lhi * 8 + j;
                const float xf = xb[((size_t)d << 13) + t];
                const unsigned rh = bf16_rne(xf);
                const float hif = __uint_as_float(rh << 16);
                const unsigned rl = bf16_rne(xf - hif);
                xbh[nt][s][j] = (short)rh;
                xbl[nt][s][j] = (short)rl;
            }
        }
    }

    // staging: pre-swizzled source byte offset (G4 swizzle, rule 21)
    const int srow = lane >> 3;
    const int soff = (srow << 7) + (((lane & 7) ^ srow) << 4);
    const int rx = ln15 & 7;
    const int c0 = (lhi ^ rx) << 3;
    const int c1 = ((4 + lhi) ^ rx) << 3;
    const int rbase = ln15 * 64;

    const int kbase = khalf << 9;

// shared staging: vgrp0 wave stages hi half, vgrp1 stages lo half (2 loads/wave)
#define STAGE(BUF, KT) { \
    const size_t tb_ = (size_t)(kbase + ((KT) << 4)) * DIM; \
    if (vgrp == 0) { \
        const unsigned char* g_ = (const unsigned char*)(ehib + tb_) + soff; \
        unsigned short* l_ = &stg[khalf][BUF][0]; \
        __builtin_amdgcn_global_load_lds((const g1_t*)g_,          (l3_t*)l_,          16, 0, 0); \
        __builtin_amdgcn_global_load_lds((const g1_t*)(g_ + 1024), (l3_t*)(l_ + 512),  16, 0, 0); \
    } else { \
        const unsigned char* g_ = (const unsigned char*)(elob + tb_) + soff; \
        unsigned short* l_ = &stg[khalf][BUF][1024]; \
        __builtin_amdgcn_global_load_lds((const g1_t*)g_,          (l3_t*)l_,          16, 0, 0); \
        __builtin_amdgcn_global_load_lds((const g1_t*)(g_ + 1024), (l3_t*)(l_ + 512),  16, 0, 0); \
    } \
}

    // packed keys: high 25 bits = positive-score float bits, low 7 = 127-local
    unsigned b1k[4] = {0, 0, 0, 0}, b2k[4] = {0, 0, 0, 0};

// BODY: counted wait -> barrier -> stage(kt+2) -> compute (tree top-2 update)
#define BODY(CBUF, KT, DOPRE, NBUF, VM) { \
    asm volatile("s_waitcnt vmcnt(" VM ")" ::: "memory");   /* own half of KT landed */ \
    asm volatile("s_barrier" ::: "memory");                 /* other half landed too */ \
    if (DOPRE) STAGE(NBUF, (KT) + 2) \
    const unsigned short* lb = &stg[khalf][CBUF][0]; \
    const short8 ah0 = *(const short8*)(lb + rbase + c0); \
    const short8 ah1 = *(const short8*)(lb + rbase + c1); \
    const short8 al0 = *(const short8*)(lb + 1024 + rbase + c0); \
    const short8 al1 = *(const short8*)(lb + 1024 + rbase + c1); \
    const int k0_ = kbase + ((KT) << 4); \
    const f32x4 bias = *(const f32x4*)(&snl[k0_ + lhi * 4]); \
    const unsigned revb = 127u - (unsigned)((KT) << 2); \
    __builtin_amdgcn_s_setprio(1); \
    _Pragma("unroll") \
    for (int nt = 0; nt < 4; nt++) { \
        f32x4 acc = bias; \
        acc = __builtin_amdgcn_mfma_f32_16x16x32_bf16(ah0, xbh[nt][0], acc, 0, 0, 0); \
        acc = __builtin_amdgcn_mfma_f32_16x16x32_bf16(ah1, xbh[nt][1], acc, 0, 0, 0); \
        acc = __builtin_amdgcn_mfma_f32_16x16x32_bf16(ah0, xbl[nt][0], acc, 0, 0, 0); \
        acc = __builtin_amdgcn_mfma_f32_16x16x32_bf16(ah1, xbl[nt][1], acc, 0, 0, 0); \
        acc = __builtin_amdgcn_mfma_f32_16x16x32_bf16(al0, xbh[nt][0], acc, 0, 0, 0); \
        acc = __builtin_amdgcn_mfma_f32_16x16x32_bf16(al1, xbh[nt][1], acc, 0, 0, 0); \
        const unsigned k0v = (__float_as_uint(acc[0]) & MSK7) | (revb - 0); \
        const unsigned k1v = (__float_as_uint(acc[1]) & MSK7) | (revb - 1); \
        const unsigned k2v = (__float_as_uint(acc[2]) & MSK7) | (revb - 2); \
        const unsigned k3v = (__float_as_uint(acc[3]) & MSK7) | (revb - 3); \
        const unsigned p01x = umx(k0v, k1v), p01n = umn(k0v, k1v); \
        const unsigned p23x = umx(k2v, k3v), p23n = umn(k2v, k3v); \
        const unsigned t4 = umx(p01x, p23x); \
        const unsigned s4 = umx(umn(p01x, p23x), umx(p01n, p23n)); \
        b2k[nt] = umx(umx(b2k[nt], s4), umn(b1k[nt], t4)); \
        b1k[nt] = umx(b1k[nt], t4); \
    } \
    __builtin_amdgcn_s_setprio(0); \
}

    STAGE(0, 0)
    STAGE(1, 1)
    #pragma unroll 1
    for (int kt3 = 0; kt3 < 30; kt3 += 3) {
        BODY(0, kt3,     1, 2, "2")
        BODY(1, kt3 + 1, 1, 0, "2")
        BODY(2, kt3 + 2, 1, 1, "2")
    }
    BODY(0, 30, 0, 0, "2")
    BODY(1, 31, 0, 0, "0")
#undef STAGE
#undef BODY

    // ---- unpack, then merge top-2 across the 4 lane-groups ----
    #pragma unroll
    for (int nt = 0; nt < 4; nt++) {
        float B1 = __uint_as_float(b1k[nt] & MSK7);
        float B2 = __uint_as_float(b2k[nt] & MSK7);
        const int local = 127 - (int)(b1k[nt] & 127u);          // kt*4 + r
        int I = kbase + ((local >> 2) << 4) + lhi * 4 + (local & 3);
        #pragma unroll
        for (int off = 16; off <= 32; off <<= 1) {
            const float o1 = __shfl_xor(B1, off, 64);
            const float o2 = __shfl_xor(B2, off, 64);
            const int   oi = __shfl_xor(I,  off, 64);
            const float nb2 = fmaxf(fminf(B1, o1), fmaxf(B2, o2));
            if (o1 > B1 || (o1 == B1 && oi < I)) { B1 = o1; I = oi; }
            B2 = nb2;
        }
        if (khalf == 1 && lane < 16) {
            const int vloc = vgrp * 64 + nt * 16 + lane;
            red[vloc][0] = B1; red[vloc][1] = B2; red[vloc][2] = __int_as_float(I);
        }
        b1k[nt] = __float_as_uint(B1); b2k[nt] = __float_as_uint(B2);
        if (lane < 16 && khalf == 0) sidx[vgrp * 64 + nt * 16 + lane] = I; // temp park
    }
    __syncthreads();

    if (khalf == 0) {
        #pragma unroll
        for (int nt = 0; nt < 4; nt++) {
            if (lane < 16) {
                const int vloc = vgrp * 64 + nt * 16 + lane;
                const float ob1 = red[vloc][0];
                const float ob2 = red[vloc][1];
                const int   oi  = __float_as_int(red[vloc][2]);
                float B1 = __uint_as_float(b1k[nt]);
                float B2 = __uint_as_float(b2k[nt]);
                int I = sidx[vloc];
                if (ob1 > B1) { B2 = fmaxf(B1, ob2); B1 = ob1; I = oi; }  // kh0 idx < kh1 idx
                else          { B2 = fmaxf(B2, ob1); }
                sidx[vloc] = (B1 - B2 <= SMARGIN) ? -1 : I;
            }
        }
    }
    __syncthreads();

    // ---- epilogue (r20 form): thread = (vector vloc, dim half dh) ----
    const int vloc = tid & 127;
    const int dh   = tid >> 7;           // 32-dim half
    const int t    = tblk + vloc;
    const int I    = sidx[vloc];
    const int v    = (b << 13) + t;

    float xf[32];
    #pragma unroll
    for (int j = 0; j < 32; j++) xf[j] = xb[((size_t)(dh * 32 + j) << 13) + t];

    if (use_xt) {                        // xT row for the code-reduce
        float4* xtp = (float4*)(xT + (size_t)v * 64 + dh * 32);
        #pragma unroll
        for (int q = 0; q < 8; q++) {
            float4 w; w.x = xf[q*4]; w.y = xf[q*4+1]; w.z = xf[q*4+2]; w.w = xf[q*4+3];
            xtp[q] = w;
        }
    }

    if (I < 0) {
        if (dh == 0) { const int p = atomicAdd(flagcnt, 1); flagids[p] = v; }
    } else {
        if (dh == 0) { idx32[v] = I; atomicAdd(&hcnt[I], 1); }
        const float4* eq4 = (const float4*)(emb + I * DIM + dh * 32);
        #pragma unroll
        for (int q = 0; q < 8; q++) {
            const float4 e4 = eq4[q];
            const int d = dh * 32 + q * 4;
            out[((size_t)b << 19) + ((size_t)(d + 0) << 13) + t] = xf[q*4+0] + (e4.x - xf[q*4+0]);
            out[((size_t)b << 19) + ((size_t)(d + 1) << 13) + t] = xf[q*4+1] + (e4.y - xf[q*4+1]);
            out[((size_t)b << 19) + ((size_t)(d + 2) << 13) + t] = xf[q*4+2] + (e4.z - xf[q*4+2]);
            out[((size_t)b << 19) + ((size_t)(d + 3) << 13) + t] = xf[q*4+3] + (e4.w - xf[q*4+3]);
        }
    }
    __syncthreads();
    #pragma unroll
    for (int q = 0; q < 4; q++) {
        const int c = hcnt[tid + q * 256];
        if (c) atomicAdd(&counts[tid + q * 256], c);
    }
}

// ---- rescan: block = 4 waves x SAME 4 vectors, k-split x4; exact fp64 ----
__global__ __launch_bounds__(256) void vq_rescan(const float* __restrict__ x,
                                                 const float* __restrict__ emb,
                                                 const double* __restrict__ e64,
                                                 const double* __restrict__ snh64,
                                                 float* __restrict__ out,
                                                 int* __restrict__ idx32,
                                                 int* __restrict__ counts,
                                                 const int* __restrict__ flagcnt,
                                                 const int* __restrict__ flagids) {
    __shared__ double rb[4][4];          // [kquarter][vx] wave best
    __shared__ int    ri[4][4];
    __shared__ int    rf[4];             // merged idx per vx
    const int tid   = threadIdx.x;
    const int wid   = tid >> 6;          // k-quarter (0..3)
    const int lane  = tid & 63;
    const int cslot = lane >> 2;         // 0..15 code slot
    const int dg    = lane & 3;          // 16-dim group
    const int count = *flagcnt;

    for (int base = blockIdx.x * 4; base < count; base += gridDim.x * 4) {
        bool act[4]; int vv[4];
        const float* xbp[4];
        double xd[4][16];
        #pragma unroll
        for (int vx = 0; vx < 4; vx++) {
            const int i = base + vx;
            act[vx] = i < count;
            const int v = flagids[act[vx] ? i : 0];
            vv[vx] = v;
            const int b = v >> 13, t = v & (T_ - 1);
            xbp[vx] = x + ((size_t)b << 19) + t;
            #pragma unroll
            for (int j = 0; j < 16; j++)
                xd[vx][j] = act[vx] ? (double)xbp[vx][(size_t)(dg * 16 + j) << 13] : 0.0;
        }

        double best[4] = {-1e300, -1e300, -1e300, -1e300};
        int    bi_[4]  = {0, 0, 0, 0};
        const int kq = wid << 8;         // this wave's 256 codes

        #pragma unroll 4
        for (int cc = 0; cc < 16; cc++) {
            const int k = kq + cc * 16 + cslot;           // in-lane k ascends with cc
            const double* ek = e64 + (size_t)k * DIM + dg * 16;
            const double snh = snh64[k];
            #pragma unroll
            for (int vx = 0; vx < 4; vx++) {
                double a0 = 0.0, a1 = 0.0, a2 = 0.0, a3 = 0.0;
                #pragma unroll
                for (int j = 0; j < 16; j += 4) {
                    a0 = __fma_rn(xd[vx][j + 0], ek[j + 0], a0);
                    a1 = __fma_rn(xd[vx][j + 1], ek[j + 1], a1);
                    a2 = __fma_rn(xd[vx][j + 2], ek[j + 2], a2);
                    a3 = __fma_rn(xd[vx][j + 3], ek[j + 3], a3);
                }
                double a = (a0 + a1) + (a2 + a3);
                a += __shfl_xor(a, 1, 64);
                a += __shfl_xor(a, 2, 64);                // full dot over 4 dim-groups
                const double m = a - snh;
                if (m > best[vx]) { best[vx] = m; bi_[vx] = k; }
            }
        }

        #pragma unroll
        for (int vx = 0; vx < 4; vx++) {
            double bb = best[vx]; int ii = bi_[vx];
            #pragma unroll
            for (int off = 4; off <= 32; off <<= 1) {     // merge across cslots
                const double ob = __shfl_xor(bb, off, 64);
                const int    oi = __shfl_xor(ii, off, 64);
                if (ob > bb || (ob == bb && oi < ii)) { bb = ob; ii = oi; }
            }
            if (lane == 0) { rb[wid][vx] = bb; ri[wid][vx] = ii; }
        }
        __syncthreads();
        if (tid < 4) {                    // thread vx: merge quarters ascending
            double bb = rb[0][tid]; int ii = ri[0][tid];
            #pragma unroll
            for (int w = 1; w < 4; w++) {
                if (rb[w][tid] > bb) { bb = rb[w][tid]; ii = ri[w][tid]; }  // strict >: lower k wins ties
            }
            rf[tid] = ii;
        }
        __syncthreads();

        {   // epilogue: wave wid handles vector wid; lane = dim
            const int vx = wid;
            if (act[vx]) {
                const int v = vv[vx];
                const int b = v >> 13, t = v & (T_ - 1);
                const int I = rf[vx];
                const float xf = xbp[vx][(size_t)lane << 13];
                out[((size_t)b << 19) + ((size_t)lane << 13) + t] =
                    xf + (emb[I * DIM + lane] - xf);
                if (lane == 0) { idx32[v] = I; atomicAdd(&counts[I], 1); }
            }
        }
        __syncthreads();                  // protect rb/ri/rf for next iteration
    }
}

// ---- scatter (scan fused, 1024 thr): scan counts, then counting-sort ----
__global__ __launch_bounds__(1024) void vq_scatter(const int* __restrict__ idx32,
                                                   const int* __restrict__ counts,
                                                   int* __restrict__ cnt2,
                                                   int* __restrict__ offsets,
                                                   int* __restrict__ order) {
    __shared__ int soff[K_CODES];
    __shared__ int wtot[16];
    const int tid  = threadIdx.x;
    const int lane = tid & 63;
    const int w    = tid >> 6;

    const int c = counts[tid];
    int s = c;
    #pragma unroll
    for (int off = 1; off < 64; off <<= 1) {
        const int o = __shfl_up(s, off, 64);
        if (lane >= off) s += o;
    }
    if (lane == 63) wtot[w] = s;
    __syncthreads();
    if (tid < 16) {
        int ws_ = wtot[tid];
        #pragma unroll
        for (int off = 1; off < 16; off <<= 1) {
            const int o = __shfl_up(ws_, off, 64);
            if (tid >= off) ws_ += o;
        }
        wtot[tid] = ws_;                 // inclusive scan of wave totals
    }
    __syncthreads();
    const int wbase = (w > 0) ? wtot[w - 1] : 0;
    soff[tid] = wbase + s - c;           // exclusive prefix
    __syncthreads();
    if (blockIdx.x == 0) offsets[tid] = soff[tid];   // publish for vq_reduce8

    const int v = blockIdx.x * 1024 + tid;
    const int k = idx32[v];
    const int p = soff[k] + atomicAdd(&cnt2[k], 1);
    order[p] = v;
}

// ---- reduce8: 8 slices per code; 4-deep gather; partials to scratch ----
__global__ __launch_bounds__(256) void vq_reduce8(const float* __restrict__ xT,
                                                  const int* __restrict__ order,
                                                  const int* __restrict__ offsets,
                                                  const int* __restrict__ counts,
                                                  float* __restrict__ partials) {
    __shared__ int lv[1024];
    __shared__ float ps[4][64];
    const int k   = blockIdx.x >> 3;
    const int sl  = blockIdx.x & 7;
    const int tid = threadIdx.x;
    const int i4  = tid >> 6;
    const int d   = tid & 63;
    const int cnt = counts[k];
    const int chunk = (cnt + 7) >> 3;
    const int lo = sl * chunk;
    const int hi = min(cnt, lo + chunk);
    const int off = offsets[k] + lo;
    const int n = hi - lo;

    float sum = 0.f;
    for (int base = 0; base < n; base += 1024) {
        const int m = min(1024, n - base);
        __syncthreads();
        for (int i = tid; i < m; i += 256) lv[i] = order[off + base + i];
        __syncthreads();
        float s0 = 0.f, s1 = 0.f, s2 = 0.f, s3 = 0.f;
        int i = i4;
        for (; i + 12 < m; i += 16) {                // 4-deep to keep loads in flight
            s0 += xT[(size_t)lv[i] * 64 + d];
            s1 += xT[(size_t)lv[i + 4] * 64 + d];
            s2 += xT[(size_t)lv[i + 8] * 64 + d];
            s3 += xT[(size_t)lv[i + 12] * 64 + d];
        }
        for (; i < m; i += 4) s0 += xT[(size_t)lv[i] * 64 + d];
        sum += (s0 + s1) + (s2 + s3);
    }
    __syncthreads();
    ps[i4][d] = sum;
    __syncthreads();
    if (i4 == 0)
        partials[(((size_t)sl << 10) + k) * 64 + d] = ps[0][d] + ps[1][d] + ps[2][d] + ps[3][d];
}

// ---- fin: sum 8 partials, divide by cluster_size ----
__global__ __launch_bounds__(64) void vq_fin(const float* __restrict__ partials,
                                             const int* __restrict__ counts,
                                             float* __restrict__ newemb) {
    const int k = blockIdx.x;
    const int d = threadIdx.x;
    float tot = 0.f;
    #pragma unroll
    for (int sl = 0; sl < 8; sl++) tot += partials[(((size_t)sl << 10) + k) * 64 + d];
    const float c = (float)counts[k];
    const float cluster = (c + EPSF) / (131072.0f + 1024.0f * EPSF) * 131072.0f;
    newemb[k * DIM + d] = tot / cluster;
}

// ---- reduce (fallback, ws too small for partials): block per code ----
__global__ __launch_bounds__(256) void vq_reduce(const float* __restrict__ x,
                                                 const float* __restrict__ xT,
                                                 const int* __restrict__ order,
                                                 const int* __restrict__ offsets,
                                                 const int* __restrict__ counts,
                                                 float* __restrict__ newemb,
                                                 int use_xt) {
    __shared__ int lv[1024];
    __shared__ float ps[4][64];
    const int k = blockIdx.x;
    const int tid = threadIdx.x;
    const int i4 = tid >> 6;
    const int d = tid & 63;
    const int off = offsets[k];
    const int cnt = counts[k];
    float sum = 0.f;
    for (int base = 0; base < cnt; base += 1024) {
        const int m = min(1024, cnt - base);
        __syncthreads();
        for (int i = tid; i < m; i += 256) lv[i] = order[off + base + i];
        __syncthreads();
        if (use_xt) {
            for (int i = i4; i < m; i += 4) sum += xT[(size_t)lv[i] * 64 + d];
        } else {
            for (int i = i4; i < m; i += 4) {
                const int v = lv[i];
                sum += x[((size_t)(v >> 13) << 19) + ((size_t)d << 13) + (v & (T_ - 1))];
            }
        }
    }
    __syncthreads();
    ps[i4][d] = sum;
    __syncthreads();
    if (i4 == 0) {
        const float tot = ps[0][d] + ps[1][d] + ps[2][d] + ps[3][d];
        const float c = (float)cnt;
        const float cluster = (c + EPSF) / (131072.0f + 1024.0f * EPSF) * 131072.0f;
        newemb[k * DIM + d] = tot / cluster;
    }
}

extern "C" void kernel_launch(void* const* d_in, const int* in_sizes, int n_in,
                              void* d_out, int out_size, void* d_ws, size_t ws_size,
                              hipStream_t stream) {
    const float* x   = (const float*)d_in[0];
    const float* emb = (const float*)d_in[1];

    char* ws = (char*)d_ws;
    double*         e64     = (double*)(ws);                  //  524288 B
    double*         snh64   = (double*)(ws + 524288);         //    8192 B
    float*          snb32   = (float*)(ws + 532480);          //    4096 B
    unsigned short* ehib    = (unsigned short*)(ws + 536576); //  131072 B
    unsigned short* elob    = (unsigned short*)(ws + 667648); //  131072 B
    int*            idx32   = (int*)(ws + 798720);            //  524288 B
    int*            order   = (int*)(ws + 1323008);           //  524288 B
    int*            counts  = (int*)(ws + 1847296);           //    4096 B
    int*            flagcnt = (int*)(ws + 1851392);           //      64 B
    int*            offsets = (int*)(ws + 1851456);           //    4096 B
    int*            cnt2    = (int*)(ws + 1855552);           //    4096 B
    int*            flagids = (int*)(ws + 1859648);           //  524288 B
    float*          xT      = (float*)(ws + 2383936);         // 33554432 B (optional)
    float*          part8   = (float*)(ws + 35938368);        //  2097152 B (optional)
    const int use_xt = (ws_size >= (size_t)2383936 + 33554432) ? 1 : 0;
    const int use_p8 = (use_xt && ws_size >= (size_t)35938368 + 2097152) ? 1 : 0;

    float* out    = (float*)d_out;
    float* newemb = out + (size_t)B_ * DIM * T_;

    vq_prep<<<K_CODES, 64, 0, stream>>>(emb, e64, snh64, snb32, ehib, elob,
                                        counts, cnt2, flagcnt);
    vq_screen<<<N_ / 128, 256, 0, stream>>>(x, ehib, elob, snb32, emb, out, xT, idx32,
                                            counts, flagcnt, flagids, use_xt);
    vq_rescan<<<2048, 256, 0, stream>>>(x, emb, e64, snh64, out, idx32, counts,
                                        flagcnt, flagids);
    vq_scatter<<<N_ / 1024, 1024, 0, stream>>>(idx32, counts, cnt2, offsets, order);
    if (use_p8) {
        vq_reduce8<<<K_CODES * 8, 256, 0, stream>>>(xT, order, offsets, counts, part8);
        vq_fin<<<K_CODES, 64, 0, stream>>>(part8, counts, newemb);
    } else {
        vq_reduce<<<K_CODES, 256, 0, stream>>>(x, xT, order, offsets, counts, newemb, use_xt);
    }
}